// Round 1
// baseline (590.317 us; speedup 1.0000x reference)
//
#include <hip/hip_runtime.h>
#include <math.h>

#define S_LEN 2048
#define BATCH 2
#define DM 1024
#define NH 16
#define DH 64
#define EPS 1e-6f

// ---------------- GEMM: O[z] = act(A @ W[z]^T + bias[z]) ----------------
// A: [M,K] row-major; W: [N,K] row-major (torch Linear weight); O: [M,N].
// blockIdx.z in {0,1,2} selects (W,bias,O); act_mask bit z enables elu(x)+1.
#define BM 64
#define BN 64
#define BK 16
#define LDSP 68   // LDS row stride: 272B = 16B-aligned, breaks pow2 banks

__global__ __launch_bounds__(256) void gemm_xwt(
    const float* __restrict__ A,
    const float* __restrict__ W0, const float* __restrict__ W1, const float* __restrict__ W2,
    const float* __restrict__ B0, const float* __restrict__ B1, const float* __restrict__ B2,
    float* __restrict__ O0, float* __restrict__ O1, float* __restrict__ O2,
    int M, int N, int K, int act_mask)
{
    const int z = blockIdx.z;
    const float* W    = (z == 0) ? W0 : (z == 1) ? W1 : W2;
    const float* bias = (z == 0) ? B0 : (z == 1) ? B1 : B2;
    float* O          = (z == 0) ? O0 : (z == 1) ? O1 : O2;
    const bool act = (act_mask >> z) & 1;

    __shared__ __align__(16) float As[BK][LDSP];   // k-major: As[k][row]
    __shared__ __align__(16) float Bs[BK][LDSP];   // k-major: Bs[k][col]

    const int tid = threadIdx.x;
    const int rowBase = blockIdx.y * BM;
    const int colBase = blockIdx.x * BN;

    // staging: one float4 per thread per matrix per K-step
    const int ldRow = tid >> 2;        // 0..63
    const int ldK0  = (tid & 3) * 4;   // 0,4,8,12

    // 4x4 micro-tile
    const int ty = tid >> 4;           // 0..15
    const int tx = tid & 15;           // 0..15
    const int r0 = ty * 4;
    const int c0 = tx * 4;

    float acc[4][4] = {};

    const float* Arow = A + (size_t)(rowBase + ldRow) * K + ldK0;
    const float* Wrow = W + (size_t)(colBase + ldRow) * K + ldK0;

    for (int k0 = 0; k0 < K; k0 += BK) {
        float4 av = *(const float4*)(Arow + k0);
        float4 wv = *(const float4*)(Wrow + k0);
        As[ldK0 + 0][ldRow] = av.x;
        As[ldK0 + 1][ldRow] = av.y;
        As[ldK0 + 2][ldRow] = av.z;
        As[ldK0 + 3][ldRow] = av.w;
        Bs[ldK0 + 0][ldRow] = wv.x;
        Bs[ldK0 + 1][ldRow] = wv.y;
        Bs[ldK0 + 2][ldRow] = wv.z;
        Bs[ldK0 + 3][ldRow] = wv.w;
        __syncthreads();
#pragma unroll
        for (int k = 0; k < BK; ++k) {
            float4 a = *(const float4*)&As[k][r0];
            float4 b = *(const float4*)&Bs[k][c0];
            float aa[4] = {a.x, a.y, a.z, a.w};
            float bb[4] = {b.x, b.y, b.z, b.w};
#pragma unroll
            for (int i = 0; i < 4; ++i)
#pragma unroll
                for (int j = 0; j < 4; ++j)
                    acc[i][j] += aa[i] * bb[j];
        }
        __syncthreads();
    }

#pragma unroll
    for (int i = 0; i < 4; ++i) {
        const int row = rowBase + r0 + i;
        const int col = colBase + c0;
        float4 o;
        float* po = &o.x;
#pragma unroll
        for (int j = 0; j < 4; ++j) {
            float v = acc[i][j] + bias[col + j];
            if (act) v = (v > 0.0f) ? (v + 1.0f) : __expf(v);  // elu(x)+1
            po[j] = v;
        }
        *(float4*)&O[(size_t)row * N + col] = o;
    }
}

// ---------------- kv = kf^T @ v, ksum = sum_j kf, per (b,h) ----------------
// grid (B*H, S/256); each block reduces 256 positions, atomicAdd to global.
__global__ __launch_bounds__(256) void kv_kernel(
    const float* __restrict__ kf, const float* __restrict__ vv,
    float* __restrict__ kv, float* __restrict__ ksum)
{
    const int bh = blockIdx.x;           // 0..31
    const int b = bh >> 4, h = bh & 15;
    const int posBase = blockIdx.y * 256;

    __shared__ __align__(16) float Ks[32][LDSP];
    __shared__ __align__(16) float Vs[32][LDSP];

    const int tid = threadIdx.x;
    const int ty = tid >> 4, tx = tid & 15;
    const int r0 = ty * 4, c0 = tx * 4;

    float acc[4][4] = {};
    float srow[4] = {};

    for (int t = 0; t < 8; ++t) {
#pragma unroll
        for (int i = 0; i < 2; ++i) {
            int l = tid + 256 * i;       // 0..511
            int p = l >> 4;              // 0..31
            int f0 = (l & 15) * 4;
            size_t g = ((size_t)(b * S_LEN + posBase + t * 32 + p)) * DM + h * DH + f0;
            float4 kq = *(const float4*)(kf + g);
            float4 vq = *(const float4*)(vv + g);
            *(float4*)&Ks[p][f0] = kq;
            *(float4*)&Vs[p][f0] = vq;
        }
        __syncthreads();
#pragma unroll
        for (int p = 0; p < 32; ++p) {
            float4 a = *(const float4*)&Ks[p][r0];
            float4 bv = *(const float4*)&Vs[p][c0];
            float aa[4] = {a.x, a.y, a.z, a.w};
            float bb[4] = {bv.x, bv.y, bv.z, bv.w};
#pragma unroll
            for (int i = 0; i < 4; ++i)
#pragma unroll
                for (int j = 0; j < 4; ++j)
                    acc[i][j] += aa[i] * bb[j];
            if (tx == 0) {
                srow[0] += aa[0]; srow[1] += aa[1];
                srow[2] += aa[2]; srow[3] += aa[3];
            }
        }
        __syncthreads();
    }
    float* kvp = kv + (size_t)bh * DH * DH;
#pragma unroll
    for (int i = 0; i < 4; ++i)
#pragma unroll
        for (int j = 0; j < 4; ++j)
            atomicAdd(&kvp[(r0 + i) * DH + c0 + j], acc[i][j]);
    if (tx == 0) {
#pragma unroll
        for (int i = 0; i < 4; ++i) atomicAdd(&ksum[bh * DH + r0 + i], srow[i]);
    }
}

// ---------------- attended = (qf @ kv) / max(qf . ksum, eps) ----------------
// grid (S/64, H, B); block handles 64 rows of one head.
__global__ __launch_bounds__(256) void attend_kernel(
    const float* __restrict__ qf, const float* __restrict__ kv,
    const float* __restrict__ ksum, float* __restrict__ att)
{
    const int sBase = blockIdx.x * 64;
    const int h = blockIdx.y;
    const int b = blockIdx.z;
    const int bh = b * NH + h;

    __shared__ __align__(16) float Qs[DH][LDSP];    // [dh][row] (transposed)
    __shared__ __align__(16) float KVs[DH][LDSP];   // [dh][col]
    __shared__ __align__(16) float ks_s[DH];
    __shared__ float den_s[64];

    const int tid = threadIdx.x;
#pragma unroll
    for (int i = 0; i < 4; ++i) {
        int l = tid + 256 * i;           // 0..1023
        int r = l >> 4;                  // 0..63
        int f0 = (l & 15) * 4;
        size_t g = ((size_t)(b * S_LEN + sBase + r)) * DM + h * DH + f0;
        float4 q4 = *(const float4*)(qf + g);
        Qs[f0 + 0][r] = q4.x;
        Qs[f0 + 1][r] = q4.y;
        Qs[f0 + 2][r] = q4.z;
        Qs[f0 + 3][r] = q4.w;
        float4 kv4 = *(const float4*)(kv + (size_t)bh * DH * DH + r * DH + f0);
        *(float4*)&KVs[r][f0] = kv4;     // here r is the kv row (= contraction dim)
    }
    if (tid < 16) {
        float4 s4 = *(const float4*)(ksum + bh * DH + tid * 4);
        *(float4*)&ks_s[tid * 4] = s4;
    }
    __syncthreads();
    if (tid < 64) {
        float d = 0.f;
#pragma unroll
        for (int f = 0; f < DH; ++f) d += Qs[f][tid] * ks_s[f];
        den_s[tid] = fmaxf(d, EPS);
    }
    __syncthreads();

    const int ty = tid >> 4, tx = tid & 15;
    const int r0 = ty * 4, c0 = tx * 4;
    float acc[4][4] = {};
#pragma unroll 8
    for (int f = 0; f < DH; ++f) {
        float4 a = *(const float4*)&Qs[f][r0];
        float4 bv = *(const float4*)&KVs[f][c0];
        float aa[4] = {a.x, a.y, a.z, a.w};
        float bb[4] = {bv.x, bv.y, bv.z, bv.w};
#pragma unroll
        for (int i = 0; i < 4; ++i)
#pragma unroll
            for (int j = 0; j < 4; ++j)
                acc[i][j] += aa[i] * bb[j];
    }
#pragma unroll
    for (int i = 0; i < 4; ++i) {
        float inv = 1.0f / den_s[r0 + i];
        float4 o;
        float* po = &o.x;
#pragma unroll
        for (int j = 0; j < 4; ++j) po[j] = acc[i][j] * inv;
        size_t g = ((size_t)(b * S_LEN + sBase + r0 + i)) * DM + h * DH + c0;
        *(float4*)&att[g] = o;
    }
}

extern "C" void kernel_launch(void* const* d_in, const int* in_sizes, int n_in,
                              void* d_out, int out_size, void* d_ws, size_t ws_size,
                              hipStream_t stream) {
    const float* x  = (const float*)d_in[0];
    const float* wq = (const float*)d_in[1];
    const float* bq = (const float*)d_in[2];
    const float* wk = (const float*)d_in[3];
    const float* bk = (const float*)d_in[4];
    const float* wv = (const float*)d_in[5];
    const float* bv = (const float*)d_in[6];
    const float* wo = (const float*)d_in[7];
    const float* bo = (const float*)d_in[8];
    float* out = (float*)d_out;

    float* ws = (float*)d_ws;
    const size_t ND = (size_t)BATCH * S_LEN * DM;   // 4,194,304 floats
    float* qf   = ws;
    float* kf   = ws + ND;
    float* vv   = ws + 2 * ND;
    float* att  = ws + 3 * ND;
    float* kvb  = ws + 4 * ND;                      // B*H*64*64 = 131072 floats
    float* ksum = kvb + (size_t)BATCH * NH * DH * DH; // 2048 floats
    // total ws use: ~67.6 MB

    const int M = BATCH * S_LEN;   // 4096

    // 1. q/k/v projections (elu+1 fused for q,k; not v)
    dim3 g1(DM / BN, M / BM, 3);
    gemm_xwt<<<g1, 256, 0, stream>>>(x, wq, wk, wv, bq, bk, bv, qf, kf, vv,
                                     M, DM, DM, 0b011);

    // 2. zero kv/ksum accumulators (ws is poisoned each call)
    hipMemsetAsync(kvb, 0,
                   ((size_t)BATCH * NH * DH * DH + (size_t)BATCH * NH * DH) * sizeof(float),
                   stream);

    // 3. kv = kf^T v, ksum = sum kf
    kv_kernel<<<dim3(BATCH * NH, S_LEN / 256), 256, 0, stream>>>(kf, vv, kvb, ksum);

    // 4. attended
    attend_kernel<<<dim3(S_LEN / 64, NH, BATCH), 256, 0, stream>>>(qf, kvb, ksum, att);

    // 5. output projection
    dim3 g5(DM / BN, M / BM, 1);
    gemm_xwt<<<g5, 256, 0, stream>>>(att, wo, wo, wo, bo, bo, bo, out, out, out,
                                     M, DM, DM, 0);
}

// Round 2
// 208.814 us; speedup vs baseline: 2.8270x; 2.8270x over previous
//
#include <hip/hip_runtime.h>
#include <math.h>

#define S_LEN 2048
#define BATCH 2
#define DM 1024
#define NH 16
#define DH 64
#define EPS 1e-6f
#define LDSP 68

typedef __attribute__((ext_vector_type(8))) short bf16x8;
typedef __attribute__((ext_vector_type(4))) float f32x4;

__device__ __forceinline__ unsigned short f2bf(float f) {
    unsigned u = __float_as_uint(f);
    u = (u + 0x7fffu + ((u >> 16) & 1u)) >> 16;
    return (unsigned short)u;
}
__device__ __forceinline__ float2 bf2f2(unsigned u) {
    float2 r;
    r.x = __uint_as_float(u << 16);
    r.y = __uint_as_float(u & 0xFFFF0000u);
    return r;
}
__device__ __forceinline__ void load16(const void* g, void* l) {
    __builtin_amdgcn_global_load_lds(
        (const __attribute__((address_space(1))) unsigned int*)g,
        (__attribute__((address_space(3))) unsigned int*)l,
        16, 0, 0);
}

// ---------------- fp32 -> bf16 conversion (x + 4 weights in one launch) ----
__global__ __launch_bounds__(256) void cvt5_bf16(
    const float* __restrict__ s0, const float* __restrict__ s1,
    const float* __restrict__ s2, const float* __restrict__ s3,
    const float* __restrict__ s4,
    unsigned short* __restrict__ d0, unsigned short* __restrict__ d1,
    unsigned short* __restrict__ d2, unsigned short* __restrict__ d3,
    unsigned short* __restrict__ d4,
    int n8_x, int n8_w)
{
    const int z = blockIdx.y;
    const float* s = (z == 0) ? s0 : (z == 1) ? s1 : (z == 2) ? s2 : (z == 3) ? s3 : s4;
    unsigned short* d = (z == 0) ? d0 : (z == 1) ? d1 : (z == 2) ? d2 : (z == 3) ? d3 : d4;
    const int n8 = (z == 0) ? n8_x : n8_w;
    int i = blockIdx.x * 256 + threadIdx.x;
    if (i >= n8) return;
    float4 a = ((const float4*)s)[2 * i];
    float4 b = ((const float4*)s)[2 * i + 1];
    uint4 o;
    o.x = (unsigned)f2bf(a.x) | ((unsigned)f2bf(a.y) << 16);
    o.y = (unsigned)f2bf(a.z) | ((unsigned)f2bf(a.w) << 16);
    o.z = (unsigned)f2bf(b.x) | ((unsigned)f2bf(b.y) << 16);
    o.w = (unsigned)f2bf(b.z) | ((unsigned)f2bf(b.w) << 16);
    ((uint4*)d)[i] = o;
}

// ---------------- MFMA GEMM: O[z] = act(A @ W[z]^T + bias[z]) -------------
// A: [M,K] bf16 row-major; W: [N,K] bf16 row-major; 128x128 tile, BK=32.
// 4 waves, each 64x64 quadrant via 4x4 grid of 16x16x32 MFMAs.
// LDS layout XOR-swizzled: chunk c (8 bf16) of row r at slot r*4 + (c ^ ((r>>1)&3)),
// keeping global_load_lds's "uniform base + lane*16" while making ds_read_b128
// fragment reads <=2-way bank aliased.
template <int OUTF32>
__global__ __launch_bounds__(256) void gemm_mfma(
    const unsigned short* __restrict__ A,
    const unsigned short* __restrict__ W0, const unsigned short* __restrict__ W1,
    const unsigned short* __restrict__ W2,
    const float* __restrict__ B0, const float* __restrict__ B1, const float* __restrict__ B2,
    void* __restrict__ O0, void* __restrict__ O1, void* __restrict__ O2,
    int M, int N, int K, int act_mask)
{
    const int z = blockIdx.z;
    const unsigned short* W = (z == 0) ? W0 : (z == 1) ? W1 : W2;
    const float* bias       = (z == 0) ? B0 : (z == 1) ? B1 : B2;
    void* O                 = (z == 0) ? O0 : (z == 1) ? O1 : O2;
    const bool act = (act_mask >> z) & 1;

    __shared__ __align__(16) unsigned short AsU[128 * 32];
    __shared__ __align__(16) unsigned short BsU[128 * 32];

    const int tid = threadIdx.x;
    const int wave = tid >> 6;
    const int lane = tid & 63;
    const int quad = lane >> 4;
    const int lm = lane & 15;
    const int wr = wave >> 1, wc = wave & 1;

    const int rowBase = blockIdx.y * 128;
    const int colBase = blockIdx.x * 128;

    // staging invariants (slot -> swizzled global chunk)
    const int s0 = wave * 128 + lane, s1 = s0 + 64;
    const int ra0 = s0 >> 2, ca0 = (s0 & 3) ^ ((ra0 >> 1) & 3);
    const int ra1 = s1 >> 2, ca1 = (s1 & 3) ^ ((ra1 >> 1) & 3);
    const unsigned short* Ag0 = A + (size_t)(rowBase + ra0) * K + ca0 * 8;
    const unsigned short* Ag1 = A + (size_t)(rowBase + ra1) * K + ca1 * 8;
    const unsigned short* Wg0 = W + (size_t)(colBase + ra0) * K + ca0 * 8;
    const unsigned short* Wg1 = W + (size_t)(colBase + ra1) * K + ca1 * 8;
    unsigned short* lA0 = AsU + (size_t)(wave * 128) * 8;       // +lane*16B by HW
    unsigned short* lA1 = AsU + (size_t)(wave * 128 + 64) * 8;
    unsigned short* lB0 = BsU + (size_t)(wave * 128) * 8;
    unsigned short* lB1 = BsU + (size_t)(wave * 128 + 64) * 8;

    // fragment read pointers (swizzled)
    const unsigned short* pA[4];
    const unsigned short* pB[4];
#pragma unroll
    for (int i = 0; i < 4; ++i) {
        int r = wr * 64 + i * 16 + lm;
        int cp = quad ^ ((r >> 1) & 3);
        pA[i] = AsU + (size_t)(r * 4 + cp) * 8;
        int n = wc * 64 + i * 16 + lm;
        int cq = quad ^ ((n >> 1) & 3);
        pB[i] = BsU + (size_t)(n * 4 + cq) * 8;
    }

    f32x4 acc[4][4];
#pragma unroll
    for (int i = 0; i < 4; ++i)
#pragma unroll
        for (int j = 0; j < 4; ++j)
            acc[i][j] = (f32x4){0.f, 0.f, 0.f, 0.f};

    for (int k0 = 0; k0 < K; k0 += 32) {
        load16(Ag0 + k0, lA0);
        load16(Ag1 + k0, lA1);
        load16(Wg0 + k0, lB0);
        load16(Wg1 + k0, lB1);
        __syncthreads();   // drains vmcnt -> LDS tiles ready
        bf16x8 aF[4], bF[4];
#pragma unroll
        for (int i = 0; i < 4; ++i) {
            aF[i] = *(const bf16x8*)pA[i];
            bF[i] = *(const bf16x8*)pB[i];
        }
#pragma unroll
        for (int i = 0; i < 4; ++i)
#pragma unroll
            for (int j = 0; j < 4; ++j)
                acc[i][j] = __builtin_amdgcn_mfma_f32_16x16x32_bf16(aF[i], bF[j], acc[i][j], 0, 0, 0);
        __syncthreads();   // LDS reuse next iter
    }

    // epilogue: C/D map col=lane&15, row=quad*4+reg
#pragma unroll
    for (int j = 0; j < 4; ++j) {
        const int col = colBase + wc * 64 + j * 16 + lm;
        const float bc = bias[col];
#pragma unroll
        for (int i = 0; i < 4; ++i) {
            const int row0 = rowBase + wr * 64 + i * 16 + quad * 4;
#pragma unroll
            for (int reg = 0; reg < 4; ++reg) {
                float v = acc[i][j][reg] + bc;
                if (act) v = (v > 0.0f) ? (v + 1.0f) : __expf(v);  // elu+1
                size_t idx = (size_t)(row0 + reg) * N + col;
                if (OUTF32) ((float*)O)[idx] = v;
                else ((unsigned short*)O)[idx] = f2bf(v);
            }
        }
    }
}

// ---------------- kv = kf^T @ v, ksum = sum_j kf (bf16 in) ----------------
__global__ __launch_bounds__(256) void kv_kernel(
    const unsigned short* __restrict__ kf, const unsigned short* __restrict__ vv,
    float* __restrict__ kv, float* __restrict__ ksum)
{
    const int bh = blockIdx.x;
    const int b = bh >> 4, h = bh & 15;
    const int posBase = blockIdx.y * 128;

    __shared__ __align__(16) float Ks[32][LDSP];
    __shared__ __align__(16) float Vs[32][LDSP];

    const int tid = threadIdx.x;
    const int ty = tid >> 4, tx = tid & 15;
    const int r0 = ty * 4, c0 = tx * 4;
    const int p = tid >> 3;            // 0..31
    const int f0 = (tid & 7) * 8;      // 0..56

    float acc[4][4] = {};
    float srow[4] = {};

    for (int t = 0; t < 4; ++t) {
        size_t g = ((size_t)(b * S_LEN + posBase + t * 32 + p)) * DM + h * DH + f0;
        uint4 kq = *(const uint4*)(kf + g);
        uint4 vq = *(const uint4*)(vv + g);
        float2 k0v = bf2f2(kq.x), k1v = bf2f2(kq.y), k2v = bf2f2(kq.z), k3v = bf2f2(kq.w);
        float2 v0v = bf2f2(vq.x), v1v = bf2f2(vq.y), v2v = bf2f2(vq.z), v3v = bf2f2(vq.w);
        *(float4*)&Ks[p][f0]     = make_float4(k0v.x, k0v.y, k1v.x, k1v.y);
        *(float4*)&Ks[p][f0 + 4] = make_float4(k2v.x, k2v.y, k3v.x, k3v.y);
        *(float4*)&Vs[p][f0]     = make_float4(v0v.x, v0v.y, v1v.x, v1v.y);
        *(float4*)&Vs[p][f0 + 4] = make_float4(v2v.x, v2v.y, v3v.x, v3v.y);
        __syncthreads();
#pragma unroll
        for (int q = 0; q < 32; ++q) {
            float4 a = *(const float4*)&Ks[q][r0];
            float4 bv = *(const float4*)&Vs[q][c0];
            float aa[4] = {a.x, a.y, a.z, a.w};
            float bb[4] = {bv.x, bv.y, bv.z, bv.w};
#pragma unroll
            for (int i = 0; i < 4; ++i)
#pragma unroll
                for (int j = 0; j < 4; ++j)
                    acc[i][j] += aa[i] * bb[j];
            if (tx == 0) {
                srow[0] += aa[0]; srow[1] += aa[1];
                srow[2] += aa[2]; srow[3] += aa[3];
            }
        }
        __syncthreads();
    }
    float* kvp = kv + (size_t)bh * DH * DH;
#pragma unroll
    for (int i = 0; i < 4; ++i)
#pragma unroll
        for (int j = 0; j < 4; ++j)
            atomicAdd(&kvp[(r0 + i) * DH + c0 + j], acc[i][j]);
    if (tx == 0) {
#pragma unroll
        for (int i = 0; i < 4; ++i) atomicAdd(&ksum[bh * DH + r0 + i], srow[i]);
    }
}

// -------- attended = (qf @ kv) / max(qf . ksum, eps), bf16 in/out ---------
__global__ __launch_bounds__(256) void attend_kernel(
    const unsigned short* __restrict__ qf, const float* __restrict__ kv,
    const float* __restrict__ ksum, unsigned short* __restrict__ att)
{
    const int sBase = blockIdx.x * 64;
    const int h = blockIdx.y;
    const int b = blockIdx.z;
    const int bh = b * NH + h;

    __shared__ __align__(16) float Qs[DH][LDSP];
    __shared__ __align__(16) float KVs[DH][LDSP];
    __shared__ __align__(16) float ks_s[DH];
    __shared__ float den_s[64];

    const int tid = threadIdx.x;
#pragma unroll
    for (int i = 0; i < 2; ++i) {
        int l = tid + 256 * i;           // 0..511
        int r = l >> 3;                  // 0..63
        int f0 = (l & 7) * 8;
        size_t g = ((size_t)(b * S_LEN + sBase + r)) * DM + h * DH + f0;
        uint4 q4 = *(const uint4*)(qf + g);
        float2 a0 = bf2f2(q4.x), a1 = bf2f2(q4.y), a2 = bf2f2(q4.z), a3 = bf2f2(q4.w);
        Qs[f0 + 0][r] = a0.x; Qs[f0 + 1][r] = a0.y;
        Qs[f0 + 2][r] = a1.x; Qs[f0 + 3][r] = a1.y;
        Qs[f0 + 4][r] = a2.x; Qs[f0 + 5][r] = a2.y;
        Qs[f0 + 6][r] = a3.x; Qs[f0 + 7][r] = a3.y;
    }
#pragma unroll
    for (int i = 0; i < 4; ++i) {
        int l = tid + 256 * i;           // 0..1023
        int r = l >> 4;
        int f0 = (l & 15) * 4;
        float4 kv4 = *(const float4*)(kv + (size_t)bh * DH * DH + r * DH + f0);
        *(float4*)&KVs[r][f0] = kv4;
    }
    if (tid < 16) {
        float4 s4 = *(const float4*)(ksum + bh * DH + tid * 4);
        *(float4*)&ks_s[tid * 4] = s4;
    }
    __syncthreads();
    if (tid < 64) {
        float d = 0.f;
#pragma unroll
        for (int f = 0; f < DH; ++f) d += Qs[f][tid] * ks_s[f];
        den_s[tid] = fmaxf(d, EPS);
    }
    __syncthreads();

    const int ty = tid >> 4, tx = tid & 15;
    const int r0 = ty * 4, c0 = tx * 4;
    float acc[4][4] = {};
#pragma unroll 8
    for (int f = 0; f < DH; ++f) {
        float4 a = *(const float4*)&Qs[f][r0];
        float4 bv = *(const float4*)&KVs[f][c0];
        float aa[4] = {a.x, a.y, a.z, a.w};
        float bb[4] = {bv.x, bv.y, bv.z, bv.w};
#pragma unroll
        for (int i = 0; i < 4; ++i)
#pragma unroll
            for (int j = 0; j < 4; ++j)
                acc[i][j] += aa[i] * bb[j];
    }
#pragma unroll
    for (int i = 0; i < 4; ++i) {
        float inv = 1.0f / den_s[r0 + i];
        ushort4 o;
        o.x = f2bf(acc[i][0] * inv);
        o.y = f2bf(acc[i][1] * inv);
        o.z = f2bf(acc[i][2] * inv);
        o.w = f2bf(acc[i][3] * inv);
        size_t g = ((size_t)(b * S_LEN + sBase + r0 + i)) * DM + h * DH + c0;
        *(ushort4*)&att[g] = o;
    }
}

extern "C" void kernel_launch(void* const* d_in, const int* in_sizes, int n_in,
                              void* d_out, int out_size, void* d_ws, size_t ws_size,
                              hipStream_t stream) {
    const float* x  = (const float*)d_in[0];
    const float* wq = (const float*)d_in[1];
    const float* bq = (const float*)d_in[2];
    const float* wk = (const float*)d_in[3];
    const float* bk = (const float*)d_in[4];
    const float* wv = (const float*)d_in[5];
    const float* bv = (const float*)d_in[6];
    const float* wo = (const float*)d_in[7];
    const float* bo = (const float*)d_in[8];
    float* out = (float*)d_out;

    const size_t ND  = (size_t)BATCH * S_LEN * DM;  // 4,194,304
    const size_t NDW = (size_t)DM * DM;             // 1,048,576

    unsigned short* x_bf  = (unsigned short*)d_ws;
    unsigned short* wq_bf = x_bf + ND;
    unsigned short* wk_bf = wq_bf + NDW;
    unsigned short* wv_bf = wk_bf + NDW;
    unsigned short* wo_bf = wv_bf + NDW;
    unsigned short* qf_bf = wo_bf + NDW;
    unsigned short* kf_bf = qf_bf + ND;
    unsigned short* vv_bf = kf_bf + ND;
    unsigned short* att_bf = vv_bf + ND;
    float* kvb  = (float*)(att_bf + ND);
    float* ksum = kvb + (size_t)BATCH * NH * DH * DH;

    const int M = BATCH * S_LEN;  // 4096
    const int n8x = (int)(ND / 8), n8w = (int)(NDW / 8);

    // 1. fp32 -> bf16 (x + 4 weights)
    cvt5_bf16<<<dim3(n8x / 256, 5), 256, 0, stream>>>(
        x, wq, wk, wv, wo, x_bf, wq_bf, wk_bf, wv_bf, wo_bf, n8x, n8w);

    // 2. q/k/v projections, MFMA, bf16 out (elu+1 on q,k)
    gemm_mfma<0><<<dim3(DM / 128, M / 128, 3), 256, 0, stream>>>(
        x_bf, wq_bf, wk_bf, wv_bf, bq, bk, bv,
        (void*)qf_bf, (void*)kf_bf, (void*)vv_bf, M, DM, DM, 0b011);

    // 3. zero kv/ksum accumulators
    hipMemsetAsync(kvb, 0,
                   ((size_t)BATCH * NH * DH * DH + (size_t)BATCH * NH * DH) * sizeof(float),
                   stream);

    // 4. kv = kf^T v, ksum = sum kf
    kv_kernel<<<dim3(BATCH * NH, S_LEN / 128), 256, 0, stream>>>(kf_bf, vv_bf, kvb, ksum);

    // 5. attended (bf16 out)
    attend_kernel<<<dim3(S_LEN / 64, NH, BATCH), 256, 0, stream>>>(qf_bf, kvb, ksum, att_bf);

    // 6. output projection, MFMA, fp32 out
    gemm_mfma<1><<<dim3(DM / 128, M / 128, 1), 256, 0, stream>>>(
        att_bf, wo_bf, wo_bf, wo_bf, bo, bo, bo,
        (void*)out, (void*)out, (void*)out, M, DM, DM, 0);
}

// Round 3
// 191.263 us; speedup vs baseline: 3.0864x; 1.0918x over previous
//
#include <hip/hip_runtime.h>
#include <math.h>

#define S_LEN 2048
#define BATCH 2
#define DM 1024
#define NH 16
#define DH 64
#define EPS 1e-6f

typedef __attribute__((ext_vector_type(8))) short bf16x8;
typedef __attribute__((ext_vector_type(4))) float f32x4;

__device__ __forceinline__ unsigned short f2bf(float f) {
    unsigned u = __float_as_uint(f);
    u = (u + 0x7fffu + ((u >> 16) & 1u)) >> 16;
    return (unsigned short)u;
}
__device__ __forceinline__ float2 bf2f2(unsigned u) {
    float2 r;
    r.x = __uint_as_float(u << 16);
    r.y = __uint_as_float(u & 0xFFFF0000u);
    return r;
}
__device__ __forceinline__ void unpack8(uint4 u, float* f) {
    float2 a = bf2f2(u.x), b = bf2f2(u.y), c = bf2f2(u.z), d = bf2f2(u.w);
    f[0] = a.x; f[1] = a.y; f[2] = b.x; f[3] = b.y;
    f[4] = c.x; f[5] = c.y; f[6] = d.x; f[7] = d.y;
}
__device__ __forceinline__ void load16(const void* g, void* l) {
    __builtin_amdgcn_global_load_lds(
        (const __attribute__((address_space(1))) unsigned int*)g,
        (__attribute__((address_space(3))) unsigned int*)l,
        16, 0, 0);
}

// ---------------- fp32 -> bf16 conversion (x + 4 weights in one launch) ----
__global__ __launch_bounds__(256) void cvt5_bf16(
    const float* __restrict__ s0, const float* __restrict__ s1,
    const float* __restrict__ s2, const float* __restrict__ s3,
    const float* __restrict__ s4,
    unsigned short* __restrict__ d0, unsigned short* __restrict__ d1,
    unsigned short* __restrict__ d2, unsigned short* __restrict__ d3,
    unsigned short* __restrict__ d4,
    int n8_x, int n8_w)
{
    const int z = blockIdx.y;
    const float* s = (z == 0) ? s0 : (z == 1) ? s1 : (z == 2) ? s2 : (z == 3) ? s3 : s4;
    unsigned short* d = (z == 0) ? d0 : (z == 1) ? d1 : (z == 2) ? d2 : (z == 3) ? d3 : d4;
    const int n8 = (z == 0) ? n8_x : n8_w;
    int i = blockIdx.x * 256 + threadIdx.x;
    if (i >= n8) return;
    float4 a = ((const float4*)s)[2 * i];
    float4 b = ((const float4*)s)[2 * i + 1];
    uint4 o;
    o.x = (unsigned)f2bf(a.x) | ((unsigned)f2bf(a.y) << 16);
    o.y = (unsigned)f2bf(a.z) | ((unsigned)f2bf(a.w) << 16);
    o.z = (unsigned)f2bf(b.x) | ((unsigned)f2bf(b.y) << 16);
    o.w = (unsigned)f2bf(b.z) | ((unsigned)f2bf(b.w) << 16);
    ((uint4*)d)[i] = o;
}

// ---------------- MFMA GEMM: O[z] = act(A @ W[z]^T + bias[z]) -------------
template <int OUTF32>
__global__ __launch_bounds__(256) void gemm_mfma(
    const unsigned short* __restrict__ A,
    const unsigned short* __restrict__ W0, const unsigned short* __restrict__ W1,
    const unsigned short* __restrict__ W2,
    const float* __restrict__ B0, const float* __restrict__ B1, const float* __restrict__ B2,
    void* __restrict__ O0, void* __restrict__ O1, void* __restrict__ O2,
    int M, int N, int K, int act_mask)
{
    const int z = blockIdx.z;
    const unsigned short* W = (z == 0) ? W0 : (z == 1) ? W1 : W2;
    const float* bias       = (z == 0) ? B0 : (z == 1) ? B1 : B2;
    void* O                 = (z == 0) ? O0 : (z == 1) ? O1 : O2;
    const bool act = (act_mask >> z) & 1;

    __shared__ __align__(16) unsigned short AsU[128 * 32];
    __shared__ __align__(16) unsigned short BsU[128 * 32];

    const int tid = threadIdx.x;
    const int wave = tid >> 6;
    const int lane = tid & 63;
    const int quad = lane >> 4;
    const int lm = lane & 15;
    const int wr = wave >> 1, wc = wave & 1;

    const int rowBase = blockIdx.y * 128;
    const int colBase = blockIdx.x * 128;

    const int s0 = wave * 128 + lane, s1 = s0 + 64;
    const int ra0 = s0 >> 2, ca0 = (s0 & 3) ^ ((ra0 >> 1) & 3);
    const int ra1 = s1 >> 2, ca1 = (s1 & 3) ^ ((ra1 >> 1) & 3);
    const unsigned short* Ag0 = A + (size_t)(rowBase + ra0) * K + ca0 * 8;
    const unsigned short* Ag1 = A + (size_t)(rowBase + ra1) * K + ca1 * 8;
    const unsigned short* Wg0 = W + (size_t)(colBase + ra0) * K + ca0 * 8;
    const unsigned short* Wg1 = W + (size_t)(colBase + ra1) * K + ca1 * 8;
    unsigned short* lA0 = AsU + (size_t)(wave * 128) * 8;
    unsigned short* lA1 = AsU + (size_t)(wave * 128 + 64) * 8;
    unsigned short* lB0 = BsU + (size_t)(wave * 128) * 8;
    unsigned short* lB1 = BsU + (size_t)(wave * 128 + 64) * 8;

    const unsigned short* pA[4];
    const unsigned short* pB[4];
#pragma unroll
    for (int i = 0; i < 4; ++i) {
        int r = wr * 64 + i * 16 + lm;
        int cp = quad ^ ((r >> 1) & 3);
        pA[i] = AsU + (size_t)(r * 4 + cp) * 8;
        int n = wc * 64 + i * 16 + lm;
        int cq = quad ^ ((n >> 1) & 3);
        pB[i] = BsU + (size_t)(n * 4 + cq) * 8;
    }

    f32x4 acc[4][4];
#pragma unroll
    for (int i = 0; i < 4; ++i)
#pragma unroll
        for (int j = 0; j < 4; ++j)
            acc[i][j] = (f32x4){0.f, 0.f, 0.f, 0.f};

    for (int k0 = 0; k0 < K; k0 += 32) {
        load16(Ag0 + k0, lA0);
        load16(Ag1 + k0, lA1);
        load16(Wg0 + k0, lB0);
        load16(Wg1 + k0, lB1);
        __syncthreads();
        bf16x8 aF[4], bF[4];
#pragma unroll
        for (int i = 0; i < 4; ++i) {
            aF[i] = *(const bf16x8*)pA[i];
            bF[i] = *(const bf16x8*)pB[i];
        }
#pragma unroll
        for (int i = 0; i < 4; ++i)
#pragma unroll
            for (int j = 0; j < 4; ++j)
                acc[i][j] = __builtin_amdgcn_mfma_f32_16x16x32_bf16(aF[i], bF[j], acc[i][j], 0, 0, 0);
        __syncthreads();
    }

#pragma unroll
    for (int j = 0; j < 4; ++j) {
        const int col = colBase + wc * 64 + j * 16 + lm;
        const float bc = bias[col];
#pragma unroll
        for (int i = 0; i < 4; ++i) {
            const int row0 = rowBase + wr * 64 + i * 16 + quad * 4;
#pragma unroll
            for (int reg = 0; reg < 4; ++reg) {
                float v = acc[i][j][reg] + bc;
                if (act) v = (v > 0.0f) ? (v + 1.0f) : __expf(v);
                size_t idx = (size_t)(row0 + reg) * N + col;
                if (OUTF32) ((float*)O)[idx] = v;
                else ((unsigned short*)O)[idx] = f2bf(v);
            }
        }
    }
}

// -------- kv partials: wave-private, barrier-free, no atomics -------------
// grid (BH=32, 4); wave w handles positions [ (by*4+w)*128, +128 ).
// Output kv_part[bh][p][e][d] (e-major = kv^T), ksum_part[bh][p][d].
__global__ __launch_bounds__(256) void kv_part_kernel(
    const unsigned short* __restrict__ kf, const unsigned short* __restrict__ vv,
    float* __restrict__ kv_part, float* __restrict__ ksum_part)
{
    const int bh = blockIdx.x;
    const int b = bh >> 4, h = bh & 15;
    const int tid = threadIdx.x;
    const int wave = tid >> 6, lane = tid & 63;
    const int p = blockIdx.y * 4 + wave;
    const int posBase = p * 128;

    __shared__ __align__(16) float Ks[4][2][16][68];
    __shared__ __align__(16) float Vs[4][2][16][68];

    const int pos_l = lane >> 3;       // 0..7
    const int f0 = (lane & 7) * 8;     // 0..56
    const int r0 = pos_l * 8;          // output d-range of this lane
    const int c0 = f0;                 // output e-range of this lane

    float acc[8][8] = {};
    float srow[8] = {};

    for (int st = 0; st < 8; ++st) {
        const int buf = st & 1;
        size_t g0 = ((size_t)(b * S_LEN + posBase + st * 16 + pos_l)) * DM + h * DH + f0;
        size_t g1 = g0 + (size_t)8 * DM;
        uint4 ka = *(const uint4*)(kf + g0);
        uint4 kb = *(const uint4*)(kf + g1);
        uint4 va = *(const uint4*)(vv + g0);
        uint4 vb = *(const uint4*)(vv + g1);
        float kaf[8], kbf[8], vaf[8], vbf[8];
        unpack8(ka, kaf); unpack8(kb, kbf); unpack8(va, vaf); unpack8(vb, vbf);
#pragma unroll
        for (int j = 0; j < 8; ++j) srow[j] += kaf[j] + kbf[j];
        *(float4*)&Ks[wave][buf][pos_l][f0]         = make_float4(kaf[0], kaf[1], kaf[2], kaf[3]);
        *(float4*)&Ks[wave][buf][pos_l][f0 + 4]     = make_float4(kaf[4], kaf[5], kaf[6], kaf[7]);
        *(float4*)&Ks[wave][buf][pos_l + 8][f0]     = make_float4(kbf[0], kbf[1], kbf[2], kbf[3]);
        *(float4*)&Ks[wave][buf][pos_l + 8][f0 + 4] = make_float4(kbf[4], kbf[5], kbf[6], kbf[7]);
        *(float4*)&Vs[wave][buf][pos_l][f0]         = make_float4(vaf[0], vaf[1], vaf[2], vaf[3]);
        *(float4*)&Vs[wave][buf][pos_l][f0 + 4]     = make_float4(vaf[4], vaf[5], vaf[6], vaf[7]);
        *(float4*)&Vs[wave][buf][pos_l + 8][f0]     = make_float4(vbf[0], vbf[1], vbf[2], vbf[3]);
        *(float4*)&Vs[wave][buf][pos_l + 8][f0 + 4] = make_float4(vbf[4], vbf[5], vbf[6], vbf[7]);
        // wave-private region: LDS ops are in-order per wave; no barrier needed
#pragma unroll 4
        for (int q = 0; q < 16; ++q) {
            float4 a0 = *(const float4*)&Ks[wave][buf][q][r0];
            float4 a1 = *(const float4*)&Ks[wave][buf][q][r0 + 4];
            float4 b0 = *(const float4*)&Vs[wave][buf][q][c0];
            float4 b1 = *(const float4*)&Vs[wave][buf][q][c0 + 4];
            float aa[8] = {a0.x, a0.y, a0.z, a0.w, a1.x, a1.y, a1.z, a1.w};
            float bb[8] = {b0.x, b0.y, b0.z, b0.w, b1.x, b1.y, b1.z, b1.w};
#pragma unroll
            for (int i = 0; i < 8; ++i)
#pragma unroll
                for (int j = 0; j < 8; ++j)
                    acc[i][j] += aa[i] * bb[j];
        }
    }

    // reduce srow across lanes sharing f0 (bits 3..5 of lane)
#pragma unroll
    for (int j = 0; j < 8; ++j) {
        srow[j] += __shfl_xor(srow[j], 8);
        srow[j] += __shfl_xor(srow[j], 16);
        srow[j] += __shfl_xor(srow[j], 32);
    }

    float* kvp = kv_part + ((size_t)bh * 16 + p) * (DH * DH);
#pragma unroll
    for (int j = 0; j < 8; ++j) {
        *(float4*)&kvp[(c0 + j) * DH + r0] =
            make_float4(acc[0][j], acc[1][j], acc[2][j], acc[3][j]);
        *(float4*)&kvp[(c0 + j) * DH + r0 + 4] =
            make_float4(acc[4][j], acc[5][j], acc[6][j], acc[7][j]);
    }
    if (pos_l == 0) {  // lanes 0..7, f0 = lane*8
        float* ksp = ksum_part + ((size_t)bh * 16 + p) * DH + f0;
        *(float4*)&ksp[0] = make_float4(srow[0], srow[1], srow[2], srow[3]);
        *(float4*)&ksp[4] = make_float4(srow[4], srow[5], srow[6], srow[7]);
    }
}

// -------- reduce 16 partials -> kvT bf16 + ksum fp32 ----------------------
__global__ __launch_bounds__(256) void kv_reduce_kernel(
    const float* __restrict__ kv_part, const float* __restrict__ ksum_part,
    unsigned short* __restrict__ kvT_bf, float* __restrict__ ksum)
{
    const int bh = blockIdx.x;
    const int tid = threadIdx.x;
    float s[16] = {};
    const float* base = kv_part + (size_t)bh * 16 * (DH * DH) + tid * 16;
#pragma unroll 4
    for (int p = 0; p < 16; ++p) {
        const float4* b4 = (const float4*)(base + (size_t)p * (DH * DH));
#pragma unroll
        for (int q = 0; q < 4; ++q) {
            float4 v = b4[q];
            s[q * 4 + 0] += v.x; s[q * 4 + 1] += v.y;
            s[q * 4 + 2] += v.z; s[q * 4 + 3] += v.w;
        }
    }
    unsigned short us[16];
#pragma unroll
    for (int i = 0; i < 16; ++i) us[i] = f2bf(s[i]);
    uint4 o0, o1;
    o0.x = (unsigned)us[0]  | ((unsigned)us[1]  << 16);
    o0.y = (unsigned)us[2]  | ((unsigned)us[3]  << 16);
    o0.z = (unsigned)us[4]  | ((unsigned)us[5]  << 16);
    o0.w = (unsigned)us[6]  | ((unsigned)us[7]  << 16);
    o1.x = (unsigned)us[8]  | ((unsigned)us[9]  << 16);
    o1.y = (unsigned)us[10] | ((unsigned)us[11] << 16);
    o1.z = (unsigned)us[12] | ((unsigned)us[13] << 16);
    o1.w = (unsigned)us[14] | ((unsigned)us[15] << 16);
    uint4* dst = (uint4*)(kvT_bf + (size_t)bh * (DH * DH) + tid * 16);
    dst[0] = o0; dst[1] = o1;
    if (tid < DH) {
        float t = 0.f;
#pragma unroll 4
        for (int p = 0; p < 16; ++p)
            t += ksum_part[((size_t)bh * 16 + p) * DH + tid];
        ksum[bh * DH + tid] = t;
    }
}

// -------- attended = (qf @ kv) / max(qf.ksum, eps), MFMA ------------------
// grid (S/128, BH). Qs/Ts staged via global_load_lds with XOR chunk swizzle:
// chunk c of row r at slot r*8 + (c ^ (r&7)) -> even bank-group spread.
__global__ __launch_bounds__(256) void attend_mfma(
    const unsigned short* __restrict__ qf, const unsigned short* __restrict__ kvT_bf,
    const float* __restrict__ ksum, unsigned short* __restrict__ att)
{
    const int sBase = blockIdx.x * 128;
    const int bh = blockIdx.y;
    const int b = bh >> 4, h = bh & 15;

    __shared__ __align__(16) unsigned short Qs[128 * 64];
    __shared__ __align__(16) unsigned short Ts[64 * 64];
    __shared__ __align__(16) float ks_s[DH];
    __shared__ float den_s[128];

    const int tid = threadIdx.x;
    const int wave = tid >> 6, lane = tid & 63;
    const int quad = lane >> 4, lm = lane & 15;

#pragma unroll
    for (int i = 0; i < 4; ++i) {
        int slot = (wave * 4 + i) * 64 + lane;
        int r = slot >> 3;
        int c = (slot & 7) ^ (r & 7);
        const unsigned short* src =
            qf + ((size_t)(b * S_LEN + sBase + r)) * DM + h * DH + c * 8;
        load16(src, Qs + (size_t)(wave * 4 + i) * 512);
    }
#pragma unroll
    for (int i = 0; i < 2; ++i) {
        int slot = (wave * 2 + i) * 64 + lane;
        int e = slot >> 3;
        int c = (slot & 7) ^ (e & 7);
        const unsigned short* src = kvT_bf + (size_t)bh * (DH * DH) + e * DH + c * 8;
        load16(src, Ts + (size_t)(wave * 2 + i) * 512);
    }
    if (tid < 16)
        *(float4*)&ks_s[tid * 4] = *(const float4*)&ksum[bh * DH + tid * 4];
    __syncthreads();

    if (tid < 128) {
        const int r = tid;
        float d = 0.f;
#pragma unroll
        for (int cxx = 0; cxx < 8; ++cxx) {
            int slot = r * 8 + (cxx ^ (r & 7));
            uint4 u = *(const uint4*)(Qs + slot * 8);
            float f[8]; unpack8(u, f);
            const float* kss = &ks_s[cxx * 8];
#pragma unroll
            for (int j = 0; j < 8; ++j) d += f[j] * kss[j];
        }
        den_s[r] = fmaxf(d, EPS);
    }
    __syncthreads();

    f32x4 acc[2][4];
#pragma unroll
    for (int ti = 0; ti < 2; ++ti)
#pragma unroll
        for (int tj = 0; tj < 4; ++tj)
            acc[ti][tj] = (f32x4){0.f, 0.f, 0.f, 0.f};

#pragma unroll
    for (int ks_i = 0; ks_i < 2; ++ks_i) {
        bf16x8 aF[2], bF[4];
#pragma unroll
        for (int ti = 0; ti < 2; ++ti) {
            int r = wave * 32 + ti * 16 + lm;
            int cx = (ks_i * 4 + quad) ^ (r & 7);
            aF[ti] = *(const bf16x8*)(Qs + (r * 8 + cx) * 8);
        }
#pragma unroll
        for (int tj = 0; tj < 4; ++tj) {
            int e = tj * 16 + lm;
            int cx = (ks_i * 4 + quad) ^ (e & 7);
            bF[tj] = *(const bf16x8*)(Ts + (e * 8 + cx) * 8);
        }
#pragma unroll
        for (int ti = 0; ti < 2; ++ti)
#pragma unroll
            for (int tj = 0; tj < 4; ++tj)
                acc[ti][tj] = __builtin_amdgcn_mfma_f32_16x16x32_bf16(aF[ti], bF[tj], acc[ti][tj], 0, 0, 0);
    }

#pragma unroll
    for (int ti = 0; ti < 2; ++ti) {
        const int rloc0 = wave * 32 + ti * 16 + quad * 4;
#pragma unroll
        for (int reg = 0; reg < 4; ++reg) {
            float inv = 1.0f / den_s[rloc0 + reg];
            unsigned short* dst =
                att + ((size_t)(b * S_LEN + sBase + rloc0 + reg)) * DM + h * DH;
#pragma unroll
            for (int tj = 0; tj < 4; ++tj)
                dst[tj * 16 + lm] = f2bf(acc[ti][tj][reg] * inv);
        }
    }
}

extern "C" void kernel_launch(void* const* d_in, const int* in_sizes, int n_in,
                              void* d_out, int out_size, void* d_ws, size_t ws_size,
                              hipStream_t stream) {
    const float* x  = (const float*)d_in[0];
    const float* wq = (const float*)d_in[1];
    const float* bq = (const float*)d_in[2];
    const float* wk = (const float*)d_in[3];
    const float* bk = (const float*)d_in[4];
    const float* wv = (const float*)d_in[5];
    const float* bv = (const float*)d_in[6];
    const float* wo = (const float*)d_in[7];
    const float* bo = (const float*)d_in[8];
    float* out = (float*)d_out;

    const size_t ND  = (size_t)BATCH * S_LEN * DM;  // 4,194,304
    const size_t NDW = (size_t)DM * DM;             // 1,048,576
    const int BH = BATCH * NH;                      // 32

    unsigned short* x_bf   = (unsigned short*)d_ws;
    unsigned short* wq_bf  = x_bf + ND;
    unsigned short* wk_bf  = wq_bf + NDW;
    unsigned short* wv_bf  = wk_bf + NDW;
    unsigned short* wo_bf  = wv_bf + NDW;
    unsigned short* qf_bf  = wo_bf + NDW;
    unsigned short* kf_bf  = qf_bf + ND;
    unsigned short* vv_bf  = kf_bf + ND;
    unsigned short* att_bf = vv_bf + ND;
    unsigned short* kvT_bf = att_bf + ND;
    float* kv_part   = (float*)(kvT_bf + (size_t)BH * DH * DH);
    float* ksum_part = kv_part + (size_t)BH * 16 * DH * DH;
    float* ksum      = ksum_part + (size_t)BH * 16 * DH;

    const int M = BATCH * S_LEN;  // 4096
    const int n8x = (int)(ND / 8), n8w = (int)(NDW / 8);

    // 1. fp32 -> bf16
    cvt5_bf16<<<dim3(n8x / 256, 5), 256, 0, stream>>>(
        x, wq, wk, wv, wo, x_bf, wq_bf, wk_bf, wv_bf, wo_bf, n8x, n8w);

    // 2. q/k/v projections, MFMA, bf16 out (elu+1 on q,k)
    gemm_mfma<0><<<dim3(DM / 128, M / 128, 3), 256, 0, stream>>>(
        x_bf, wq_bf, wk_bf, wv_bf, bq, bk, bv,
        (void*)qf_bf, (void*)kf_bf, (void*)vv_bf, M, DM, DM, 0b011);

    // 3. kv partials (no atomics, no memset)
    kv_part_kernel<<<dim3(BH, 4), 256, 0, stream>>>(kf_bf, vv_bf, kv_part, ksum_part);

    // 4. reduce -> kvT bf16 + ksum fp32
    kv_reduce_kernel<<<BH, 256, 0, stream>>>(kv_part, ksum_part, kvT_bf, ksum);

    // 5. attended (MFMA, bf16 out)
    attend_mfma<<<dim3(S_LEN / 128, BH), 256, 0, stream>>>(qf_bf, kvT_bf, ksum, att_bf);

    // 6. output projection, MFMA, fp32 out
    gemm_mfma<1><<<dim3(DM / 128, M / 128, 1), 256, 0, stream>>>(
        att_bf, wo_bf, wo_bf, wo_bf, bo, bo, bo,
        (void*)out, (void*)out, (void*)out, M, DM, DM, 0);
}

// Round 4
// 180.521 us; speedup vs baseline: 3.2701x; 1.0595x over previous
//
#include <hip/hip_runtime.h>
#include <math.h>

#define S_LEN 2048
#define BATCH 2
#define DM 1024
#define NH 16
#define DH 64
#define EPS 1e-6f

typedef __attribute__((ext_vector_type(8))) short bf16x8;
typedef __attribute__((ext_vector_type(4))) float f32x4;

__device__ __forceinline__ unsigned short f2bf(float f) {
    unsigned u = __float_as_uint(f);
    u = (u + 0x7fffu + ((u >> 16) & 1u)) >> 16;
    return (unsigned short)u;
}
__device__ __forceinline__ float2 bf2f2(unsigned u) {
    float2 r;
    r.x = __uint_as_float(u << 16);
    r.y = __uint_as_float(u & 0xFFFF0000u);
    return r;
}
__device__ __forceinline__ void unpack8(uint4 u, float* f) {
    float2 a = bf2f2(u.x), b = bf2f2(u.y), c = bf2f2(u.z), d = bf2f2(u.w);
    f[0] = a.x; f[1] = a.y; f[2] = b.x; f[3] = b.y;
    f[4] = c.x; f[5] = c.y; f[6] = d.x; f[7] = d.y;
}
__device__ __forceinline__ void load16(const void* g, void* l) {
    __builtin_amdgcn_global_load_lds(
        (const __attribute__((address_space(1))) unsigned int*)g,
        (__attribute__((address_space(3))) unsigned int*)l,
        16, 0, 0);
}

// ---------------- fp32 -> bf16, flat grid (no idle blocks) ----------------
// units of 8 elems: x = 524288 units, each weight = 131072 units.
__global__ __launch_bounds__(256) void cvt_flat(
    const float* __restrict__ x,
    const float* __restrict__ wq, const float* __restrict__ wk,
    const float* __restrict__ wv, const float* __restrict__ wo,
    unsigned short* __restrict__ x_bf,
    unsigned short* __restrict__ wq_bf, unsigned short* __restrict__ wk_bf,
    unsigned short* __restrict__ wv_bf, unsigned short* __restrict__ wo_bf)
{
    int u = blockIdx.x * 256 + threadIdx.x;   // 0 .. 1048575
    const float* s;
    unsigned short* d;
    int off;
    if (u < 524288) {
        s = x; d = x_bf; off = u;
    } else {
        int v = u - 524288;
        int w = v >> 17;          // 0..3
        off = v & 131071;
        s = (w == 0) ? wq : (w == 1) ? wk : (w == 2) ? wv : wo;
        d = (w == 0) ? wq_bf : (w == 1) ? wk_bf : (w == 2) ? wv_bf : wo_bf;
    }
    float4 a = ((const float4*)s)[2 * off];
    float4 b = ((const float4*)s)[2 * off + 1];
    uint4 o;
    o.x = (unsigned)f2bf(a.x) | ((unsigned)f2bf(a.y) << 16);
    o.y = (unsigned)f2bf(a.z) | ((unsigned)f2bf(a.w) << 16);
    o.z = (unsigned)f2bf(b.x) | ((unsigned)f2bf(b.y) << 16);
    o.w = (unsigned)f2bf(b.z) | ((unsigned)f2bf(b.w) << 16);
    ((uint4*)d)[off] = o;
}

// ---------------- MFMA GEMM: O[z] = act(A @ W[z]^T + bias[z]) -------------
// 128x128 tile, BK=32, 4 waves x (4x4 of 16x16x32). Unchanged from r3.
__global__ __launch_bounds__(256) void gemm_qkv(
    const unsigned short* __restrict__ A,
    const unsigned short* __restrict__ W0, const unsigned short* __restrict__ W1,
    const unsigned short* __restrict__ W2,
    const float* __restrict__ B0, const float* __restrict__ B1, const float* __restrict__ B2,
    unsigned short* __restrict__ O0, unsigned short* __restrict__ O1,
    unsigned short* __restrict__ O2,
    int M, int N, int K, int act_mask)
{
    const int z = blockIdx.z;
    const unsigned short* W = (z == 0) ? W0 : (z == 1) ? W1 : W2;
    const float* bias       = (z == 0) ? B0 : (z == 1) ? B1 : B2;
    unsigned short* O       = (z == 0) ? O0 : (z == 1) ? O1 : O2;
    const bool act = (act_mask >> z) & 1;

    __shared__ __align__(16) unsigned short AsU[128 * 32];
    __shared__ __align__(16) unsigned short BsU[128 * 32];

    const int tid = threadIdx.x;
    const int wave = tid >> 6;
    const int lane = tid & 63;
    const int quad = lane >> 4;
    const int lm = lane & 15;
    const int wr = wave >> 1, wc = wave & 1;

    const int rowBase = blockIdx.y * 128;
    const int colBase = blockIdx.x * 128;

    const int s0 = wave * 128 + lane, s1 = s0 + 64;
    const int ra0 = s0 >> 2, ca0 = (s0 & 3) ^ ((ra0 >> 1) & 3);
    const int ra1 = s1 >> 2, ca1 = (s1 & 3) ^ ((ra1 >> 1) & 3);
    const unsigned short* Ag0 = A + (size_t)(rowBase + ra0) * K + ca0 * 8;
    const unsigned short* Ag1 = A + (size_t)(rowBase + ra1) * K + ca1 * 8;
    const unsigned short* Wg0 = W + (size_t)(colBase + ra0) * K + ca0 * 8;
    const unsigned short* Wg1 = W + (size_t)(colBase + ra1) * K + ca1 * 8;
    unsigned short* lA0 = AsU + (size_t)(wave * 128) * 8;
    unsigned short* lA1 = AsU + (size_t)(wave * 128 + 64) * 8;
    unsigned short* lB0 = BsU + (size_t)(wave * 128) * 8;
    unsigned short* lB1 = BsU + (size_t)(wave * 128 + 64) * 8;

    const unsigned short* pA[4];
    const unsigned short* pB[4];
#pragma unroll
    for (int i = 0; i < 4; ++i) {
        int r = wr * 64 + i * 16 + lm;
        int cp = quad ^ ((r >> 1) & 3);
        pA[i] = AsU + (size_t)(r * 4 + cp) * 8;
        int n = wc * 64 + i * 16 + lm;
        int cq = quad ^ ((n >> 1) & 3);
        pB[i] = BsU + (size_t)(n * 4 + cq) * 8;
    }

    f32x4 acc[4][4];
#pragma unroll
    for (int i = 0; i < 4; ++i)
#pragma unroll
        for (int j = 0; j < 4; ++j)
            acc[i][j] = (f32x4){0.f, 0.f, 0.f, 0.f};

    for (int k0 = 0; k0 < K; k0 += 32) {
        load16(Ag0 + k0, lA0);
        load16(Ag1 + k0, lA1);
        load16(Wg0 + k0, lB0);
        load16(Wg1 + k0, lB1);
        __syncthreads();
        bf16x8 aF[4], bF[4];
#pragma unroll
        for (int i = 0; i < 4; ++i) {
            aF[i] = *(const bf16x8*)pA[i];
            bF[i] = *(const bf16x8*)pB[i];
        }
#pragma unroll
        for (int i = 0; i < 4; ++i)
#pragma unroll
            for (int j = 0; j < 4; ++j)
                acc[i][j] = __builtin_amdgcn_mfma_f32_16x16x32_bf16(aF[i], bF[j], acc[i][j], 0, 0, 0);
        __syncthreads();
    }

#pragma unroll
    for (int j = 0; j < 4; ++j) {
        const int col = colBase + wc * 64 + j * 16 + lm;
        const float bc = bias[col];
#pragma unroll
        for (int i = 0; i < 4; ++i) {
            const int row0 = rowBase + wr * 64 + i * 16 + quad * 4;
#pragma unroll
            for (int reg = 0; reg < 4; ++reg) {
                float v = acc[i][j][reg] + bc;
                if (act) v = (v > 0.0f) ? (v + 1.0f) : __expf(v);
                O[(size_t)(row0 + reg) * N + col] = f2bf(v);
            }
        }
    }
}

// ---------------- out-proj GEMM: 64x128 tile -> 512 blocks (2/CU) ---------
__global__ __launch_bounds__(256) void gemm_out(
    const unsigned short* __restrict__ A,   // att bf16 [M x K]
    const unsigned short* __restrict__ W,   // wo bf16 [N x K]
    const float* __restrict__ bias,
    float* __restrict__ O, int M, int N, int K)
{
    __shared__ __align__(16) unsigned short AsU[64 * 32];
    __shared__ __align__(16) unsigned short BsU[128 * 32];

    const int tid = threadIdx.x;
    const int wave = tid >> 6;
    const int lane = tid & 63;
    const int quad = lane >> 4;
    const int lm = lane & 15;
    const int wr = wave >> 1, wc = wave & 1;

    const int rowBase = blockIdx.y * 64;
    const int colBase = blockIdx.x * 128;

    // A staging: 256 slots, 1 per thread
    const int sA = tid;
    const int rA = sA >> 2, cA = (sA & 3) ^ ((rA >> 1) & 3);
    const unsigned short* Ag = A + (size_t)(rowBase + rA) * K + cA * 8;
    unsigned short* lA = AsU + (size_t)(wave * 64) * 8;
    // B staging: 512 slots, 2 per thread
    const int s0 = wave * 128 + lane, s1 = s0 + 64;
    const int rb0 = s0 >> 2, cb0 = (s0 & 3) ^ ((rb0 >> 1) & 3);
    const int rb1 = s1 >> 2, cb1 = (s1 & 3) ^ ((rb1 >> 1) & 3);
    const unsigned short* Wg0 = W + (size_t)(colBase + rb0) * K + cb0 * 8;
    const unsigned short* Wg1 = W + (size_t)(colBase + rb1) * K + cb1 * 8;
    unsigned short* lB0 = BsU + (size_t)(wave * 128) * 8;
    unsigned short* lB1 = BsU + (size_t)(wave * 128 + 64) * 8;

    const unsigned short* pA[2];
    const unsigned short* pB[4];
#pragma unroll
    for (int i = 0; i < 2; ++i) {
        int r = wr * 32 + i * 16 + lm;
        int cp = quad ^ ((r >> 1) & 3);
        pA[i] = AsU + (size_t)(r * 4 + cp) * 8;
    }
#pragma unroll
    for (int j = 0; j < 4; ++j) {
        int n = wc * 64 + j * 16 + lm;
        int cq = quad ^ ((n >> 1) & 3);
        pB[j] = BsU + (size_t)(n * 4 + cq) * 8;
    }

    f32x4 acc[2][4];
#pragma unroll
    for (int i = 0; i < 2; ++i)
#pragma unroll
        for (int j = 0; j < 4; ++j)
            acc[i][j] = (f32x4){0.f, 0.f, 0.f, 0.f};

    for (int k0 = 0; k0 < K; k0 += 32) {
        load16(Ag + k0, lA);
        load16(Wg0 + k0, lB0);
        load16(Wg1 + k0, lB1);
        __syncthreads();
        bf16x8 aF[2], bF[4];
#pragma unroll
        for (int i = 0; i < 2; ++i) aF[i] = *(const bf16x8*)pA[i];
#pragma unroll
        for (int j = 0; j < 4; ++j) bF[j] = *(const bf16x8*)pB[j];
#pragma unroll
        for (int i = 0; i < 2; ++i)
#pragma unroll
            for (int j = 0; j < 4; ++j)
                acc[i][j] = __builtin_amdgcn_mfma_f32_16x16x32_bf16(aF[i], bF[j], acc[i][j], 0, 0, 0);
        __syncthreads();
    }

#pragma unroll
    for (int j = 0; j < 4; ++j) {
        const int col = colBase + wc * 64 + j * 16 + lm;
        const float bc = bias[col];
#pragma unroll
        for (int i = 0; i < 2; ++i) {
            const int row0 = rowBase + wr * 32 + i * 16 + quad * 4;
#pragma unroll
            for (int reg = 0; reg < 4; ++reg)
                O[(size_t)(row0 + reg) * N + col] = acc[i][j][reg] + bc;
        }
    }
}

// -------- kv partials: wave-private compute + in-block reduction ----------
// grid (BH=32, 4): block computes 4 wave-partials over 512 positions, reduces
// them in reused LDS, writes ONE fp32 partial [64e x 64d] + ksum partial.
__global__ __launch_bounds__(256) void kv_part_kernel(
    const unsigned short* __restrict__ kf, const unsigned short* __restrict__ vv,
    float* __restrict__ kv_part, float* __restrict__ ksum_part)
{
    const int bh = blockIdx.x;
    const int b = bh >> 4, h = bh & 15;
    const int tid = threadIdx.x;
    const int wave = tid >> 6, lane = tid & 63;
    const int blk = blockIdx.y;             // 0..3
    const int posBase = (blk * 4 + wave) * 128;

    // 69632 B: Ks/Vs during main loop, reduction scratch afterwards.
    __shared__ __align__(16) float smem[17408];
    float (*Ks)[2][16][68] = (float (*)[2][16][68])smem;           // [4][2][16][68]
    float (*Vs)[2][16][68] = (float (*)[2][16][68])(smem + 8704);

    const int pos_l = lane >> 3;       // 0..7
    const int f0 = (lane & 7) * 8;     // 0..56
    const int r0 = pos_l * 8;          // d-range of this lane
    const int c0 = f0;                 // e-range of this lane

    float acc[8][8] = {};
    float srow[8] = {};

    for (int st = 0; st < 8; ++st) {
        const int buf = st & 1;
        size_t g0 = ((size_t)(b * S_LEN + posBase + st * 16 + pos_l)) * DM + h * DH + f0;
        size_t g1 = g0 + (size_t)8 * DM;
        uint4 ka = *(const uint4*)(kf + g0);
        uint4 kb = *(const uint4*)(kf + g1);
        uint4 va = *(const uint4*)(vv + g0);
        uint4 vb = *(const uint4*)(vv + g1);
        float kaf[8], kbf[8], vaf[8], vbf[8];
        unpack8(ka, kaf); unpack8(kb, kbf); unpack8(va, vaf); unpack8(vb, vbf);
#pragma unroll
        for (int j = 0; j < 8; ++j) srow[j] += kaf[j] + kbf[j];
        *(float4*)&Ks[wave][buf][pos_l][f0]         = make_float4(kaf[0], kaf[1], kaf[2], kaf[3]);
        *(float4*)&Ks[wave][buf][pos_l][f0 + 4]     = make_float4(kaf[4], kaf[5], kaf[6], kaf[7]);
        *(float4*)&Ks[wave][buf][pos_l + 8][f0]     = make_float4(kbf[0], kbf[1], kbf[2], kbf[3]);
        *(float4*)&Ks[wave][buf][pos_l + 8][f0 + 4] = make_float4(kbf[4], kbf[5], kbf[6], kbf[7]);
        *(float4*)&Vs[wave][buf][pos_l][f0]         = make_float4(vaf[0], vaf[1], vaf[2], vaf[3]);
        *(float4*)&Vs[wave][buf][pos_l][f0 + 4]     = make_float4(vaf[4], vaf[5], vaf[6], vaf[7]);
        *(float4*)&Vs[wave][buf][pos_l + 8][f0]     = make_float4(vbf[0], vbf[1], vbf[2], vbf[3]);
        *(float4*)&Vs[wave][buf][pos_l + 8][f0 + 4] = make_float4(vbf[4], vbf[5], vbf[6], vbf[7]);
        // wave-private LDS region: per-wave in-order, no barrier needed
#pragma unroll 4
        for (int q = 0; q < 16; ++q) {
            float4 a0 = *(const float4*)&Ks[wave][buf][q][r0];
            float4 a1 = *(const float4*)&Ks[wave][buf][q][r0 + 4];
            float4 b0 = *(const float4*)&Vs[wave][buf][q][c0];
            float4 b1 = *(const float4*)&Vs[wave][buf][q][c0 + 4];
            float aa[8] = {a0.x, a0.y, a0.z, a0.w, a1.x, a1.y, a1.z, a1.w};
            float bb[8] = {b0.x, b0.y, b0.z, b0.w, b1.x, b1.y, b1.z, b1.w};
#pragma unroll
            for (int i = 0; i < 8; ++i)
#pragma unroll
                for (int j = 0; j < 8; ++j)
                    acc[i][j] += aa[i] * bb[j];
        }
    }

    // srow: reduce across lanes sharing f0
#pragma unroll
    for (int j = 0; j < 8; ++j) {
        srow[j] += __shfl_xor(srow[j], 8);
        srow[j] += __shfl_xor(srow[j], 16);
        srow[j] += __shfl_xor(srow[j], 32);
    }

    // ---- in-block reduction of the 4 wave-partials (LDS reuse) ----
    __syncthreads();   // all waves done with Ks/Vs
    float* red = smem;                     // [4][64e][64d] = 16384 floats
    float* ksred = smem + 16384;           // [4][64]
#pragma unroll
    for (int j = 0; j < 8; ++j) {
        *(float4*)&red[wave * 4096 + (c0 + j) * 64 + r0] =
            make_float4(acc[0][j], acc[1][j], acc[2][j], acc[3][j]);
        *(float4*)&red[wave * 4096 + (c0 + j) * 64 + r0 + 4] =
            make_float4(acc[4][j], acc[5][j], acc[6][j], acc[7][j]);
    }
    if (pos_l == 0) {
        *(float4*)&ksred[wave * 64 + f0]     = make_float4(srow[0], srow[1], srow[2], srow[3]);
        *(float4*)&ksred[wave * 64 + f0 + 4] = make_float4(srow[4], srow[5], srow[6], srow[7]);
    }
    __syncthreads();

    float* outp = kv_part + ((size_t)bh * 4 + blk) * 4096;
    const int base = tid * 16;
#pragma unroll
    for (int g = 0; g < 4; ++g) {
        float4 s0 = *(const float4*)&red[base + g * 4];
        float4 s1 = *(const float4*)&red[4096 + base + g * 4];
        float4 s2 = *(const float4*)&red[8192 + base + g * 4];
        float4 s3 = *(const float4*)&red[12288 + base + g * 4];
        float4 o = make_float4(s0.x + s1.x + s2.x + s3.x,
                               s0.y + s1.y + s2.y + s3.y,
                               s0.z + s1.z + s2.z + s3.z,
                               s0.w + s1.w + s2.w + s3.w);
        *(float4*)&outp[base + g * 4] = o;
    }
    if (tid < 64) {
        float t = ksred[tid] + ksred[64 + tid] + ksred[128 + tid] + ksred[192 + tid];
        ksum_part[((size_t)bh * 4 + blk) * 64 + tid] = t;
    }
}

// -------- attend: reduce 4 kv partials + MFMA (qf @ kv) / denom -----------
// grid (S/128, BH). Q staged via global_load_lds (XOR chunk swizzle);
// Ts built in-kernel from fp32 partial sums.
__global__ __launch_bounds__(256) void attend_mfma(
    const unsigned short* __restrict__ qf, const float* __restrict__ kv_part,
    const float* __restrict__ ksum_part, unsigned short* __restrict__ att)
{
    const int sBase = blockIdx.x * 128;
    const int bh = blockIdx.y;
    const int b = bh >> 4, h = bh & 15;

    __shared__ __align__(16) unsigned short Qs[128 * 64];
    __shared__ __align__(16) unsigned short Ts[64 * 64];
    __shared__ __align__(16) float ks_s[DH];
    __shared__ float den_s[128];

    const int tid = threadIdx.x;
    const int wave = tid >> 6, lane = tid & 63;
    const int quad = lane >> 4, lm = lane & 15;

    // Q staging (swizzled global_load_lds)
#pragma unroll
    for (int i = 0; i < 4; ++i) {
        int slot = (wave * 4 + i) * 64 + lane;
        int r = slot >> 3;
        int c = (slot & 7) ^ (r & 7);
        const unsigned short* src =
            qf + ((size_t)(b * S_LEN + sBase + r)) * DM + h * DH + c * 8;
        load16(src, Qs + (size_t)(wave * 4 + i) * 512);
    }

    // Ts: sum 4 fp32 partials -> bf16, swizzled ds_write
    {
        const int e = tid >> 2, c2 = tid & 3;
        const float* kp = kv_part + (size_t)bh * 4 * 4096 + e * 64 + c2 * 16;
        float s[16];
#pragma unroll
        for (int g = 0; g < 4; ++g) {
            float4 p0 = *(const float4*)(kp + g * 4);
            float4 p1 = *(const float4*)(kp + 4096 + g * 4);
            float4 p2 = *(const float4*)(kp + 8192 + g * 4);
            float4 p3 = *(const float4*)(kp + 12288 + g * 4);
            s[g * 4 + 0] = p0.x + p1.x + p2.x + p3.x;
            s[g * 4 + 1] = p0.y + p1.y + p2.y + p3.y;
            s[g * 4 + 2] = p0.z + p1.z + p2.z + p3.z;
            s[g * 4 + 3] = p0.w + p1.w + p2.w + p3.w;
        }
        unsigned short us[16];
#pragma unroll
        for (int i = 0; i < 16; ++i) us[i] = f2bf(s[i]);
        uint4 lo, hi;
        lo.x = (unsigned)us[0]  | ((unsigned)us[1]  << 16);
        lo.y = (unsigned)us[2]  | ((unsigned)us[3]  << 16);
        lo.z = (unsigned)us[4]  | ((unsigned)us[5]  << 16);
        lo.w = (unsigned)us[6]  | ((unsigned)us[7]  << 16);
        hi.x = (unsigned)us[8]  | ((unsigned)us[9]  << 16);
        hi.y = (unsigned)us[10] | ((unsigned)us[11] << 16);
        hi.z = (unsigned)us[12] | ((unsigned)us[13] << 16);
        hi.w = (unsigned)us[14] | ((unsigned)us[15] << 16);
        const int cL = c2 * 2, cH = c2 * 2 + 1;
        *(uint4*)(Ts + (size_t)(e * 8 + (cL ^ (e & 7))) * 8) = lo;
        *(uint4*)(Ts + (size_t)(e * 8 + (cH ^ (e & 7))) * 8) = hi;
    }
    // ksum final
    if (tid < 64) {
        const float* kq = ksum_part + (size_t)bh * 4 * 64 + tid;
        ks_s[tid] = kq[0] + kq[64] + kq[128] + kq[192];
    }
    __syncthreads();

    if (tid < 128) {
        const int r = tid;
        float d = 0.f;
#pragma unroll
        for (int cxx = 0; cxx < 8; ++cxx) {
            int slot = r * 8 + (cxx ^ (r & 7));
            uint4 u = *(const uint4*)(Qs + slot * 8);
            float f[8]; unpack8(u, f);
            const float* kss = &ks_s[cxx * 8];
#pragma unroll
            for (int j = 0; j < 8; ++j) d += f[j] * kss[j];
        }
        den_s[r] = fmaxf(d, EPS);
    }
    __syncthreads();

    f32x4 acc[2][4];
#pragma unroll
    for (int ti = 0; ti < 2; ++ti)
#pragma unroll
        for (int tj = 0; tj < 4; ++tj)
            acc[ti][tj] = (f32x4){0.f, 0.f, 0.f, 0.f};

#pragma unroll
    for (int ks_i = 0; ks_i < 2; ++ks_i) {
        bf16x8 aF[2], bF[4];
#pragma unroll
        for (int ti = 0; ti < 2; ++ti) {
            int r = wave * 32 + ti * 16 + lm;
            int cx = (ks_i * 4 + quad) ^ (r & 7);
            aF[ti] = *(const bf16x8*)(Qs + (r * 8 + cx) * 8);
        }
#pragma unroll
        for (int tj = 0; tj < 4; ++tj) {
            int e = tj * 16 + lm;
            int cx = (ks_i * 4 + quad) ^ (e & 7);
            bF[tj] = *(const bf16x8*)(Ts + (e * 8 + cx) * 8);
        }
#pragma unroll
        for (int ti = 0; ti < 2; ++ti)
#pragma unroll
            for (int tj = 0; tj < 4; ++tj)
                acc[ti][tj] = __builtin_amdgcn_mfma_f32_16x16x32_bf16(aF[ti], bF[tj], acc[ti][tj], 0, 0, 0);
    }

#pragma unroll
    for (int ti = 0; ti < 2; ++ti) {
        const int rloc0 = wave * 32 + ti * 16 + quad * 4;
#pragma unroll
        for (int reg = 0; reg < 4; ++reg) {
            float inv = 1.0f / den_s[rloc0 + reg];
            unsigned short* dst =
                att + ((size_t)(b * S_LEN + sBase + rloc0 + reg)) * DM + h * DH;
#pragma unroll
            for (int tj = 0; tj < 4; ++tj)
                dst[tj * 16 + lm] = f2bf(acc[ti][tj][reg] * inv);
        }
    }
}

extern "C" void kernel_launch(void* const* d_in, const int* in_sizes, int n_in,
                              void* d_out, int out_size, void* d_ws, size_t ws_size,
                              hipStream_t stream) {
    const float* x  = (const float*)d_in[0];
    const float* wq = (const float*)d_in[1];
    const float* bq = (const float*)d_in[2];
    const float* wk = (const float*)d_in[3];
    const float* bk = (const float*)d_in[4];
    const float* wv = (const float*)d_in[5];
    const float* bv = (const float*)d_in[6];
    const float* wo = (const float*)d_in[7];
    const float* bo = (const float*)d_in[8];
    float* out = (float*)d_out;

    const size_t ND  = (size_t)BATCH * S_LEN * DM;  // 4,194,304
    const size_t NDW = (size_t)DM * DM;             // 1,048,576
    const int BH = BATCH * NH;                      // 32

    unsigned short* x_bf   = (unsigned short*)d_ws;
    unsigned short* wq_bf  = x_bf + ND;
    unsigned short* wk_bf  = wq_bf + NDW;
    unsigned short* wv_bf  = wk_bf + NDW;
    unsigned short* wo_bf  = wv_bf + NDW;
    unsigned short* qf_bf  = wo_bf + NDW;
    unsigned short* kf_bf  = qf_bf + ND;
    unsigned short* vv_bf  = kf_bf + ND;
    unsigned short* att_bf = vv_bf + ND;
    float* kv_part   = (float*)(att_bf + ND);               // BH*4*4096 floats
    float* ksum_part = kv_part + (size_t)BH * 4 * 4096;     // BH*4*64 floats

    const int M = BATCH * S_LEN;  // 4096

    // 1. fp32 -> bf16 (flat grid: 1048576 units / 256)
    cvt_flat<<<4096, 256, 0, stream>>>(x, wq, wk, wv, wo,
                                       x_bf, wq_bf, wk_bf, wv_bf, wo_bf);

    // 2. q/k/v projections (elu+1 on q,k)
    gemm_qkv<<<dim3(DM / 128, M / 128, 3), 256, 0, stream>>>(
        x_bf, wq_bf, wk_bf, wv_bf, bq, bk, bv,
        qf_bf, kf_bf, vv_bf, M, DM, DM, 0b011);

    // 3. kv partials (block-reduced: 4 per bh)
    kv_part_kernel<<<dim3(BH, 4), 256, 0, stream>>>(kf_bf, vv_bf, kv_part, ksum_part);

    // 4. attend (reduces partials in staging, MFMA, bf16 out)
    attend_mfma<<<dim3(S_LEN / 128, BH), 256, 0, stream>>>(qf_bf, kv_part, ksum_part, att_bf);

    // 5. output projection (64x128 tiles -> 512 blocks)
    gemm_out<<<dim3(DM / 128, M / 64), 256, 0, stream>>>(
        att_bf, wo_bf, bo, out, M, DM, DM);
}

// Round 5
// 169.874 us; speedup vs baseline: 3.4750x; 1.0627x over previous
//
#include <hip/hip_runtime.h>
#include <math.h>

#define S_LEN 2048
#define BATCH 2
#define DM 1024
#define NH 16
#define DH 64
#define EPS 1e-6f

typedef __attribute__((ext_vector_type(8))) short bf16x8;
typedef __attribute__((ext_vector_type(4))) float f32x4;

__device__ __forceinline__ unsigned short f2bf(float f) {
    unsigned u = __float_as_uint(f);
    u = (u + 0x7fffu + ((u >> 16) & 1u)) >> 16;
    return (unsigned short)u;
}
__device__ __forceinline__ float2 bf2f2(unsigned u) {
    float2 r;
    r.x = __uint_as_float(u << 16);
    r.y = __uint_as_float(u & 0xFFFF0000u);
    return r;
}
__device__ __forceinline__ void unpack8(uint4 u, float* f) {
    float2 a = bf2f2(u.x), b = bf2f2(u.y), c = bf2f2(u.z), d = bf2f2(u.w);
    f[0] = a.x; f[1] = a.y; f[2] = b.x; f[3] = b.y;
    f[4] = c.x; f[5] = c.y; f[6] = d.x; f[7] = d.y;
}
__device__ __forceinline__ void load16(const void* g, void* l) {
    __builtin_amdgcn_global_load_lds(
        (const __attribute__((address_space(1))) unsigned int*)g,
        (__attribute__((address_space(3))) unsigned int*)l,
        16, 0, 0);
}

// ---------------- fp32 -> bf16, flat grid ----------------
__global__ __launch_bounds__(256) void cvt_flat(
    const float* __restrict__ x,
    const float* __restrict__ wq, const float* __restrict__ wk,
    const float* __restrict__ wv, const float* __restrict__ wo,
    unsigned short* __restrict__ x_bf,
    unsigned short* __restrict__ wq_bf, unsigned short* __restrict__ wk_bf,
    unsigned short* __restrict__ wv_bf, unsigned short* __restrict__ wo_bf)
{
    int u = blockIdx.x * 256 + threadIdx.x;   // 0 .. 1048575
    const float* s;
    unsigned short* d;
    int off;
    if (u < 524288) {
        s = x; d = x_bf; off = u;
    } else {
        int v = u - 524288;
        int w = v >> 17;          // 0..3
        off = v & 131071;
        s = (w == 0) ? wq : (w == 1) ? wk : (w == 2) ? wv : wo;
        d = (w == 0) ? wq_bf : (w == 1) ? wk_bf : (w == 2) ? wv_bf : wo_bf;
    }
    float4 a = ((const float4*)s)[2 * off];
    float4 b = ((const float4*)s)[2 * off + 1];
    uint4 o;
    o.x = (unsigned)f2bf(a.x) | ((unsigned)f2bf(a.y) << 16);
    o.y = (unsigned)f2bf(a.z) | ((unsigned)f2bf(a.w) << 16);
    o.z = (unsigned)f2bf(b.x) | ((unsigned)f2bf(b.y) << 16);
    o.w = (unsigned)f2bf(b.z) | ((unsigned)f2bf(b.w) << 16);
    ((uint4*)d)[off] = o;
}

// ---------------- MFMA GEMM qkv: 128x128 tile, BK=64 ----------------------
// LDS swizzle: chunk c (8 bf16) of row r at slot r*8 + (c ^ (r&7)).
// Staging: slot s -> r=s>>3, c=(s&7)^((s>>3)&7); wave-uniform base + lane*16.
// Halved barrier/drain count vs BK=32 (16 K-iters, 32 MFMA each).
__global__ __launch_bounds__(256) void gemm_qkv(
    const unsigned short* __restrict__ A,
    const unsigned short* __restrict__ W0, const unsigned short* __restrict__ W1,
    const unsigned short* __restrict__ W2,
    const float* __restrict__ B0, const float* __restrict__ B1, const float* __restrict__ B2,
    unsigned short* __restrict__ O0, unsigned short* __restrict__ O1,
    unsigned short* __restrict__ O2,
    int M, int N, int K, int act_mask)
{
    const int z = blockIdx.z;
    const unsigned short* W = (z == 0) ? W0 : (z == 1) ? W1 : W2;
    const float* bias       = (z == 0) ? B0 : (z == 1) ? B1 : B2;
    unsigned short* O       = (z == 0) ? O0 : (z == 1) ? O1 : O2;
    const bool act = (act_mask >> z) & 1;

    __shared__ __align__(16) unsigned short AsU[128 * 64];  // 16 KB
    __shared__ __align__(16) unsigned short BsU[128 * 64];  // 16 KB

    const int tid = threadIdx.x;
    const int wave = tid >> 6;
    const int lane = tid & 63;
    const int quad = lane >> 4;
    const int lm = lane & 15;
    const int wr = wave >> 1, wc = wave & 1;

    const int rowBase = blockIdx.y * 128;
    const int colBase = blockIdx.x * 128;

    // staging: 1024 slots/matrix, 4 wave-instructions per wave per matrix
    const int cS = (lane & 7) ^ ((lane >> 3) & 7);   // iter-invariant chunk
    const unsigned short* Ag[4];
    const unsigned short* Wg[4];
    unsigned short* lA[4];
    unsigned short* lB[4];
#pragma unroll
    for (int i = 0; i < 4; ++i) {
        int rS = (wave * 4 + i) * 8 + (lane >> 3);
        Ag[i] = A + (size_t)(rowBase + rS) * K + cS * 8;
        Wg[i] = W + (size_t)(colBase + rS) * K + cS * 8;
        lA[i] = AsU + (size_t)((wave * 4 + i) * 64) * 8;
        lB[i] = BsU + (size_t)((wave * 4 + i) * 64) * 8;
    }

    // fragment pointers: [row i][ks]
    const unsigned short* pA[4][2];
    const unsigned short* pB[4][2];
#pragma unroll
    for (int i = 0; i < 4; ++i) {
        int rA = wr * 64 + i * 16 + lm;
        int rB = wc * 64 + i * 16 + lm;
#pragma unroll
        for (int ks = 0; ks < 2; ++ks) {
            pA[i][ks] = AsU + (size_t)(rA * 8 + ((ks * 4 + quad) ^ (rA & 7))) * 8;
            pB[i][ks] = BsU + (size_t)(rB * 8 + ((ks * 4 + quad) ^ (rB & 7))) * 8;
        }
    }

    f32x4 acc[4][4];
#pragma unroll
    for (int i = 0; i < 4; ++i)
#pragma unroll
        for (int j = 0; j < 4; ++j)
            acc[i][j] = (f32x4){0.f, 0.f, 0.f, 0.f};

    for (int k0 = 0; k0 < K; k0 += 64) {
#pragma unroll
        for (int i = 0; i < 4; ++i) {
            load16(Ag[i] + k0, lA[i]);
            load16(Wg[i] + k0, lB[i]);
        }
        __syncthreads();
#pragma unroll
        for (int ks = 0; ks < 2; ++ks) {
            bf16x8 aF[4], bF[4];
#pragma unroll
            for (int i = 0; i < 4; ++i) {
                aF[i] = *(const bf16x8*)pA[i][ks];
                bF[i] = *(const bf16x8*)pB[i][ks];
            }
#pragma unroll
            for (int i = 0; i < 4; ++i)
#pragma unroll
                for (int j = 0; j < 4; ++j)
                    acc[i][j] = __builtin_amdgcn_mfma_f32_16x16x32_bf16(aF[i], bF[j], acc[i][j], 0, 0, 0);
        }
        __syncthreads();
    }

#pragma unroll
    for (int j = 0; j < 4; ++j) {
        const int col = colBase + wc * 64 + j * 16 + lm;
        const float bc = bias[col];
#pragma unroll
        for (int i = 0; i < 4; ++i) {
            const int row0 = rowBase + wr * 64 + i * 16 + quad * 4;
#pragma unroll
            for (int reg = 0; reg < 4; ++reg) {
                float v = acc[i][j][reg] + bc;
                if (act) v = (v > 0.0f) ? (v + 1.0f) : __expf(v);
                O[(size_t)(row0 + reg) * N + col] = f2bf(v);
            }
        }
    }
}

// ---------------- out-proj GEMM: 64x128 tile, BK=64 -----------------------
__global__ __launch_bounds__(256) void gemm_out(
    const unsigned short* __restrict__ A,   // att bf16 [M x K]
    const unsigned short* __restrict__ W,   // wo bf16 [N x K]
    const float* __restrict__ bias,
    float* __restrict__ O, int M, int N, int K)
{
    __shared__ __align__(16) unsigned short AsU[64 * 64];    // 8 KB
    __shared__ __align__(16) unsigned short BsU[128 * 64];   // 16 KB

    const int tid = threadIdx.x;
    const int wave = tid >> 6;
    const int lane = tid & 63;
    const int quad = lane >> 4;
    const int lm = lane & 15;
    const int wr = wave >> 1, wc = wave & 1;

    const int rowBase = blockIdx.y * 64;
    const int colBase = blockIdx.x * 128;

    const int cS = (lane & 7) ^ ((lane >> 3) & 7);
    const unsigned short* Ag[2];
    const unsigned short* Wg[4];
    unsigned short* lA[2];
    unsigned short* lB[4];
#pragma unroll
    for (int i = 0; i < 2; ++i) {
        int rS = (wave * 2 + i) * 8 + (lane >> 3);
        Ag[i] = A + (size_t)(rowBase + rS) * K + cS * 8;
        lA[i] = AsU + (size_t)((wave * 2 + i) * 64) * 8;
    }
#pragma unroll
    for (int i = 0; i < 4; ++i) {
        int rS = (wave * 4 + i) * 8 + (lane >> 3);
        Wg[i] = W + (size_t)(colBase + rS) * K + cS * 8;
        lB[i] = BsU + (size_t)((wave * 4 + i) * 64) * 8;
    }

    const unsigned short* pA[2][2];
    const unsigned short* pB[4][2];
#pragma unroll
    for (int i = 0; i < 2; ++i) {
        int rA = wr * 32 + i * 16 + lm;
#pragma unroll
        for (int ks = 0; ks < 2; ++ks)
            pA[i][ks] = AsU + (size_t)(rA * 8 + ((ks * 4 + quad) ^ (rA & 7))) * 8;
    }
#pragma unroll
    for (int j = 0; j < 4; ++j) {
        int rB = wc * 64 + j * 16 + lm;
#pragma unroll
        for (int ks = 0; ks < 2; ++ks)
            pB[j][ks] = BsU + (size_t)(rB * 8 + ((ks * 4 + quad) ^ (rB & 7))) * 8;
    }

    f32x4 acc[2][4];
#pragma unroll
    for (int i = 0; i < 2; ++i)
#pragma unroll
        for (int j = 0; j < 4; ++j)
            acc[i][j] = (f32x4){0.f, 0.f, 0.f, 0.f};

    for (int k0 = 0; k0 < K; k0 += 64) {
#pragma unroll
        for (int i = 0; i < 2; ++i) load16(Ag[i] + k0, lA[i]);
#pragma unroll
        for (int i = 0; i < 4; ++i) load16(Wg[i] + k0, lB[i]);
        __syncthreads();
#pragma unroll
        for (int ks = 0; ks < 2; ++ks) {
            bf16x8 aF[2], bF[4];
#pragma unroll
            for (int i = 0; i < 2; ++i) aF[i] = *(const bf16x8*)pA[i][ks];
#pragma unroll
            for (int j = 0; j < 4; ++j) bF[j] = *(const bf16x8*)pB[j][ks];
#pragma unroll
            for (int i = 0; i < 2; ++i)
#pragma unroll
                for (int j = 0; j < 4; ++j)
                    acc[i][j] = __builtin_amdgcn_mfma_f32_16x16x32_bf16(aF[i], bF[j], acc[i][j], 0, 0, 0);
        }
        __syncthreads();
    }

#pragma unroll
    for (int j = 0; j < 4; ++j) {
        const int col = colBase + wc * 64 + j * 16 + lm;
        const float bc = bias[col];
#pragma unroll
        for (int i = 0; i < 2; ++i) {
            const int row0 = rowBase + wr * 32 + i * 16 + quad * 4;
#pragma unroll
            for (int reg = 0; reg < 4; ++reg)
                O[(size_t)(row0 + reg) * N + col] = acc[i][j][reg] + bc;
        }
    }
}

// -------- kv partials: wave-private compute + in-block reduction ----------
__global__ __launch_bounds__(256) void kv_part_kernel(
    const unsigned short* __restrict__ kf, const unsigned short* __restrict__ vv,
    float* __restrict__ kv_part, float* __restrict__ ksum_part)
{
    const int bh = blockIdx.x;
    const int b = bh >> 4, h = bh & 15;
    const int tid = threadIdx.x;
    const int wave = tid >> 6, lane = tid & 63;
    const int blk = blockIdx.y;             // 0..3
    const int posBase = (blk * 4 + wave) * 128;

    __shared__ __align__(16) float smem[17408];
    float (*Ks)[2][16][68] = (float (*)[2][16][68])smem;
    float (*Vs)[2][16][68] = (float (*)[2][16][68])(smem + 8704);

    const int pos_l = lane >> 3;
    const int f0 = (lane & 7) * 8;
    const int r0 = pos_l * 8;
    const int c0 = f0;

    float acc[8][8] = {};
    float srow[8] = {};

    for (int st = 0; st < 8; ++st) {
        const int buf = st & 1;
        size_t g0 = ((size_t)(b * S_LEN + posBase + st * 16 + pos_l)) * DM + h * DH + f0;
        size_t g1 = g0 + (size_t)8 * DM;
        uint4 ka = *(const uint4*)(kf + g0);
        uint4 kb = *(const uint4*)(kf + g1);
        uint4 va = *(const uint4*)(vv + g0);
        uint4 vb = *(const uint4*)(vv + g1);
        float kaf[8], kbf[8], vaf[8], vbf[8];
        unpack8(ka, kaf); unpack8(kb, kbf); unpack8(va, vaf); unpack8(vb, vbf);
#pragma unroll
        for (int j = 0; j < 8; ++j) srow[j] += kaf[j] + kbf[j];
        *(float4*)&Ks[wave][buf][pos_l][f0]         = make_float4(kaf[0], kaf[1], kaf[2], kaf[3]);
        *(float4*)&Ks[wave][buf][pos_l][f0 + 4]     = make_float4(kaf[4], kaf[5], kaf[6], kaf[7]);
        *(float4*)&Ks[wave][buf][pos_l + 8][f0]     = make_float4(kbf[0], kbf[1], kbf[2], kbf[3]);
        *(float4*)&Ks[wave][buf][pos_l + 8][f0 + 4] = make_float4(kbf[4], kbf[5], kbf[6], kbf[7]);
        *(float4*)&Vs[wave][buf][pos_l][f0]         = make_float4(vaf[0], vaf[1], vaf[2], vaf[3]);
        *(float4*)&Vs[wave][buf][pos_l][f0 + 4]     = make_float4(vaf[4], vaf[5], vaf[6], vaf[7]);
        *(float4*)&Vs[wave][buf][pos_l + 8][f0]     = make_float4(vbf[0], vbf[1], vbf[2], vbf[3]);
        *(float4*)&Vs[wave][buf][pos_l + 8][f0 + 4] = make_float4(vbf[4], vbf[5], vbf[6], vbf[7]);
#pragma unroll 4
        for (int q = 0; q < 16; ++q) {
            float4 a0 = *(const float4*)&Ks[wave][buf][q][r0];
            float4 a1 = *(const float4*)&Ks[wave][buf][q][r0 + 4];
            float4 b0 = *(const float4*)&Vs[wave][buf][q][c0];
            float4 b1 = *(const float4*)&Vs[wave][buf][q][c0 + 4];
            float aa[8] = {a0.x, a0.y, a0.z, a0.w, a1.x, a1.y, a1.z, a1.w};
            float bb[8] = {b0.x, b0.y, b0.z, b0.w, b1.x, b1.y, b1.z, b1.w};
#pragma unroll
            for (int i = 0; i < 8; ++i)
#pragma unroll
                for (int j = 0; j < 8; ++j)
                    acc[i][j] += aa[i] * bb[j];
        }
    }

#pragma unroll
    for (int j = 0; j < 8; ++j) {
        srow[j] += __shfl_xor(srow[j], 8);
        srow[j] += __shfl_xor(srow[j], 16);
        srow[j] += __shfl_xor(srow[j], 32);
    }

    __syncthreads();
    float* red = smem;
    float* ksred = smem + 16384;
#pragma unroll
    for (int j = 0; j < 8; ++j) {
        *(float4*)&red[wave * 4096 + (c0 + j) * 64 + r0] =
            make_float4(acc[0][j], acc[1][j], acc[2][j], acc[3][j]);
        *(float4*)&red[wave * 4096 + (c0 + j) * 64 + r0 + 4] =
            make_float4(acc[4][j], acc[5][j], acc[6][j], acc[7][j]);
    }
    if (pos_l == 0) {
        *(float4*)&ksred[wave * 64 + f0]     = make_float4(srow[0], srow[1], srow[2], srow[3]);
        *(float4*)&ksred[wave * 64 + f0 + 4] = make_float4(srow[4], srow[5], srow[6], srow[7]);
    }
    __syncthreads();

    float* outp = kv_part + ((size_t)bh * 4 + blk) * 4096;
    const int base = tid * 16;
#pragma unroll
    for (int g = 0; g < 4; ++g) {
        float4 s0 = *(const float4*)&red[base + g * 4];
        float4 s1 = *(const float4*)&red[4096 + base + g * 4];
        float4 s2 = *(const float4*)&red[8192 + base + g * 4];
        float4 s3 = *(const float4*)&red[12288 + base + g * 4];
        float4 o = make_float4(s0.x + s1.x + s2.x + s3.x,
                               s0.y + s1.y + s2.y + s3.y,
                               s0.z + s1.z + s2.z + s3.z,
                               s0.w + s1.w + s2.w + s3.w);
        *(float4*)&outp[base + g * 4] = o;
    }
    if (tid < 64) {
        float t = ksred[tid] + ksred[64 + tid] + ksred[128 + tid] + ksred[192 + tid];
        ksum_part[((size_t)bh * 4 + blk) * 64 + tid] = t;
    }
}

// -------- attend: reduce 4 kv partials + MFMA (qf @ kv) / denom -----------
__global__ __launch_bounds__(256) void attend_mfma(
    const unsigned short* __restrict__ qf, const float* __restrict__ kv_part,
    const float* __restrict__ ksum_part, unsigned short* __restrict__ att)
{
    const int sBase = blockIdx.x * 128;
    const int bh = blockIdx.y;
    const int b = bh >> 4, h = bh & 15;

    __shared__ __align__(16) unsigned short Qs[128 * 64];
    __shared__ __align__(16) unsigned short Ts[64 * 64];
    __shared__ __align__(16) float ks_s[DH];
    __shared__ float den_s[128];

    const int tid = threadIdx.x;
    const int wave = tid >> 6, lane = tid & 63;
    const int quad = lane >> 4, lm = lane & 15;

#pragma unroll
    for (int i = 0; i < 4; ++i) {
        int slot = (wave * 4 + i) * 64 + lane;
        int r = slot >> 3;
        int c = (slot & 7) ^ (r & 7);
        const unsigned short* src =
            qf + ((size_t)(b * S_LEN + sBase + r)) * DM + h * DH + c * 8;
        load16(src, Qs + (size_t)(wave * 4 + i) * 512);
    }

    {
        const int e = tid >> 2, c2 = tid & 3;
        const float* kp = kv_part + (size_t)bh * 4 * 4096 + e * 64 + c2 * 16;
        float s[16];
#pragma unroll
        for (int g = 0; g < 4; ++g) {
            float4 p0 = *(const float4*)(kp + g * 4);
            float4 p1 = *(const float4*)(kp + 4096 + g * 4);
            float4 p2 = *(const float4*)(kp + 8192 + g * 4);
            float4 p3 = *(const float4*)(kp + 12288 + g * 4);
            s[g * 4 + 0] = p0.x + p1.x + p2.x + p3.x;
            s[g * 4 + 1] = p0.y + p1.y + p2.y + p3.y;
            s[g * 4 + 2] = p0.z + p1.z + p2.z + p3.z;
            s[g * 4 + 3] = p0.w + p1.w + p2.w + p3.w;
        }
        unsigned short us[16];
#pragma unroll
        for (int i = 0; i < 16; ++i) us[i] = f2bf(s[i]);
        uint4 lo, hi;
        lo.x = (unsigned)us[0]  | ((unsigned)us[1]  << 16);
        lo.y = (unsigned)us[2]  | ((unsigned)us[3]  << 16);
        lo.z = (unsigned)us[4]  | ((unsigned)us[5]  << 16);
        lo.w = (unsigned)us[6]  | ((unsigned)us[7]  << 16);
        hi.x = (unsigned)us[8]  | ((unsigned)us[9]  << 16);
        hi.y = (unsigned)us[10] | ((unsigned)us[11] << 16);
        hi.z = (unsigned)us[12] | ((unsigned)us[13] << 16);
        hi.w = (unsigned)us[14] | ((unsigned)us[15] << 16);
        const int cL = c2 * 2, cH = c2 * 2 + 1;
        *(uint4*)(Ts + (size_t)(e * 8 + (cL ^ (e & 7))) * 8) = lo;
        *(uint4*)(Ts + (size_t)(e * 8 + (cH ^ (e & 7))) * 8) = hi;
    }
    if (tid < 64) {
        const float* kq = ksum_part + (size_t)bh * 4 * 64 + tid;
        ks_s[tid] = kq[0] + kq[64] + kq[128] + kq[192];
    }
    __syncthreads();

    if (tid < 128) {
        const int r = tid;
        float d = 0.f;
#pragma unroll
        for (int cxx = 0; cxx < 8; ++cxx) {
            int slot = r * 8 + (cxx ^ (r & 7));
            uint4 u = *(const uint4*)(Qs + slot * 8);
            float f[8]; unpack8(u, f);
            const float* kss = &ks_s[cxx * 8];
#pragma unroll
            for (int j = 0; j < 8; ++j) d += f[j] * kss[j];
        }
        den_s[r] = fmaxf(d, EPS);
    }
    __syncthreads();

    f32x4 acc[2][4];
#pragma unroll
    for (int ti = 0; ti < 2; ++ti)
#pragma unroll
        for (int tj = 0; tj < 4; ++tj)
            acc[ti][tj] = (f32x4){0.f, 0.f, 0.f, 0.f};

#pragma unroll
    for (int ks_i = 0; ks_i < 2; ++ks_i) {
        bf16x8 aF[2], bF[4];
#pragma unroll
        for (int ti = 0; ti < 2; ++ti) {
            int r = wave * 32 + ti * 16 + lm;
            int cx = (ks_i * 4 + quad) ^ (r & 7);
            aF[ti] = *(const bf16x8*)(Qs + (r * 8 + cx) * 8);
        }
#pragma unroll
        for (int tj = 0; tj < 4; ++tj) {
            int e = tj * 16 + lm;
            int cx = (ks_i * 4 + quad) ^ (e & 7);
            bF[tj] = *(const bf16x8*)(Ts + (e * 8 + cx) * 8);
        }
#pragma unroll
        for (int ti = 0; ti < 2; ++ti)
#pragma unroll
            for (int tj = 0; tj < 4; ++tj)
                acc[ti][tj] = __builtin_amdgcn_mfma_f32_16x16x32_bf16(aF[ti], bF[tj], acc[ti][tj], 0, 0, 0);
    }

#pragma unroll
    for (int ti = 0; ti < 2; ++ti) {
        const int rloc0 = wave * 32 + ti * 16 + quad * 4;
#pragma unroll
        for (int reg = 0; reg < 4; ++reg) {
            float inv = 1.0f / den_s[rloc0 + reg];
            unsigned short* dst =
                att + ((size_t)(b * S_LEN + sBase + rloc0 + reg)) * DM + h * DH;
#pragma unroll
            for (int tj = 0; tj < 4; ++tj)
                dst[tj * 16 + lm] = f2bf(acc[ti][tj][reg] * inv);
        }
    }
}

extern "C" void kernel_launch(void* const* d_in, const int* in_sizes, int n_in,
                              void* d_out, int out_size, void* d_ws, size_t ws_size,
                              hipStream_t stream) {
    const float* x  = (const float*)d_in[0];
    const float* wq = (const float*)d_in[1];
    const float* bq = (const float*)d_in[2];
    const float* wk = (const float*)d_in[3];
    const float* bk = (const float*)d_in[4];
    const float* wv = (const float*)d_in[5];
    const float* bv = (const float*)d_in[6];
    const float* wo = (const float*)d_in[7];
    const float* bo = (const float*)d_in[8];
    float* out = (float*)d_out;

    const size_t ND  = (size_t)BATCH * S_LEN * DM;  // 4,194,304
    const size_t NDW = (size_t)DM * DM;             // 1,048,576
    const int BH = BATCH * NH;                      // 32

    unsigned short* x_bf   = (unsigned short*)d_ws;
    unsigned short* wq_bf  = x_bf + ND;
    unsigned short* wk_bf  = wq_bf + NDW;
    unsigned short* wv_bf  = wk_bf + NDW;
    unsigned short* wo_bf  = wv_bf + NDW;
    unsigned short* qf_bf  = wo_bf + NDW;
    unsigned short* kf_bf  = qf_bf + ND;
    unsigned short* vv_bf  = kf_bf + ND;
    unsigned short* att_bf = vv_bf + ND;
    float* kv_part   = (float*)(att_bf + ND);
    float* ksum_part = kv_part + (size_t)BH * 4 * 4096;

    const int M = BATCH * S_LEN;  // 4096

    // 1. fp32 -> bf16
    cvt_flat<<<4096, 256, 0, stream>>>(x, wq, wk, wv, wo,
                                       x_bf, wq_bf, wk_bf, wv_bf, wo_bf);

    // 2. q/k/v projections (elu+1 on q,k), BK=64
    gemm_qkv<<<dim3(DM / 128, M / 128, 3), 256, 0, stream>>>(
        x_bf, wq_bf, wk_bf, wv_bf, bq, bk, bv,
        qf_bf, kf_bf, vv_bf, M, DM, DM, 0b011);

    // 3. kv partials
    kv_part_kernel<<<dim3(BH, 4), 256, 0, stream>>>(kf_bf, vv_bf, kv_part, ksum_part);

    // 4. attend
    attend_mfma<<<dim3(S_LEN / 128, BH), 256, 0, stream>>>(qf_bf, kv_part, ksum_part, att_bf);

    // 5. output projection, BK=64
    gemm_out<<<dim3(DM / 128, M / 64), 256, 0, stream>>>(
        att_bf, wo_bf, bo, out, M, DM, DM);
}